// Round 7
// baseline (368.501 us; speedup 1.0000x reference)
//
#include <hip/hip_runtime.h>

#define NB 8
#define CIN 512
#define OIN 256
#define HWN 9216
#define KP 110
#define SCL 0.10206207261596577f  // 9216^(-0.25)

typedef __attribute__((ext_vector_type(8))) short bf16x8;
typedef __attribute__((ext_vector_type(4))) float f32x4;
typedef unsigned short u16;

__device__ inline unsigned bf16_1(float a) {
    unsigned u = __builtin_bit_cast(unsigned, a);
    return (u + 0x7fffu + ((u >> 16) & 1u)) >> 16;
}
__device__ inline unsigned bf16_pack(float a, float b) {
    return bf16_1(a) | (bf16_1(b) << 16);
}
__device__ inline float b2f(u16 u) {
    return __builtin_bit_cast(float, ((unsigned)u) << 16);
}

__device__ __forceinline__ void gload16(const u16* g, u16* l) {
    __builtin_amdgcn_global_load_lds(
        (const __attribute__((address_space(1))) unsigned int*)g,
        (__attribute__((address_space(3))) unsigned int*)l, 16, 0, 0);
}

// ---------------------------------------------------------------------------
// Weight cast: phi_w+theta_w -> Wcat bf16 [512][512]; W_w -> Wwb bf16 [512][256]
// ---------------------------------------------------------------------------
__global__ __launch_bounds__(256) void castw_kernel(
    const float* __restrict__ phi_w, const float* __restrict__ theta_w,
    const float* __restrict__ Ww,
    u16* __restrict__ Wcat, u16* __restrict__ Wwb)
{
    int i = blockIdx.x * 256 + threadIdx.x;
    if (i < 262144) {
        float v = (i < 131072) ? phi_w[i] : theta_w[i - 131072];
        Wcat[i] = (u16)bf16_1(v);
    } else {
        int j = i - 262144;
        Wwb[j] = (u16)bf16_1(Ww[j]);
    }
}

// ---------------------------------------------------------------------------
// castx: x fp32 [b][512 c][9216 hw] -> xT bf16 [b][9216 hw][512 c]
// ---------------------------------------------------------------------------
__global__ __launch_bounds__(256) void castx_kernel(
    const float* __restrict__ x, u16* __restrict__ xT)
{
    const int t = threadIdx.x;
    const int tx = t & 15, ty = t >> 4;
    const int b = blockIdx.z;
    const int c0 = blockIdx.y * 64;
    const int hw0 = blockIdx.x * 64;

    const float* xb = x + ((size_t)b * CIN + c0 + ty * 4) * HWN + hw0 + tx * 4;
    float4 v[4];
#pragma unroll
    for (int q = 0; q < 4; ++q)
        v[q] = *(const float4*)(xb + (size_t)q * HWN);

    u16* dst = xT + ((size_t)b * HWN + hw0 + tx * 4) * CIN + c0 + ty * 4;
    const float* f = (const float*)v;
#pragma unroll
    for (int p = 0; p < 4; ++p) {
        uint2 o = {bf16_pack(f[0 * 4 + p], f[1 * 4 + p]),
                   bf16_pack(f[2 * 4 + p], f[3 * 4 + p])};
        *(uint2*)(dst + (size_t)p * CIN) = o;
    }
}

// ---------------------------------------------------------------------------
// MFMA GEMM, double-buffered (T3 minimum 2-phase) + XCD swizzle (T1):
//   D[m=hw][n=o] = sum_k A[m][k] * Bw[n][k]   (per batch)
//   1D grid of 72*4*NB blocks; per K-step: issue next-tile global_load_lds,
//   compute current from LDS, vmcnt(0)+raw barrier (prefetch latency hidden).
// ---------------------------------------------------------------------------
template<int KDIM, int MODE>
__global__ __launch_bounds__(256) void gemm_kernel(
    const u16* __restrict__ A,
    const u16* __restrict__ Bw,
    const float* __restrict__ b0, const float* __restrict__ b1,
    const float* __restrict__ resid,
    void* __restrict__ out0_, void* __restrict__ out1_)
{
    __shared__ u16 As[2][128 * 64];
    __shared__ u16 Bs[2][128 * 64];

    constexpr int NSTEP = KDIM / 64;
    constexpr int NWG = 72 * 4 * NB;

    // bijective XCD swizzle: consecutive hardware blocks (round-robin XCDs)
    // map to one XCD-contiguous chunk = one batch's full m x n tile grid.
    const int id = blockIdx.x;
    const int swz = (id & 7) * (NWG / 8) + (id >> 3);
    const int bx = swz % 72;
    const int by = (swz / 72) & 3;
    const int bz = swz / 288;

    const int t = threadIdx.x;
    const int m0 = bx * 128;
    const int n0 = by * 128;
    const int w = t >> 6, l = t & 63;
    const int wr = w >> 1, wc = w & 1;
    const int g = l >> 4, li = l & 15;

    const u16* Ab = A + (size_t)bz * HWN * KDIM;

    const int srow = t >> 3;
    const int su = t & 7;

    f32x4 zero = {0.f, 0.f, 0.f, 0.f};
    f32x4 acc[4][4];
#pragma unroll
    for (int i = 0; i < 4; ++i)
#pragma unroll
        for (int j = 0; j < 4; ++j) acc[i][j] = zero;

    // ---- prologue: stage step 0 into buffer 0 ----
#pragma unroll
    for (int cc = 0; cc < 4; ++cc) {
        int row = cc * 32 + srow;
        int ss = su ^ (row & 7);
        gload16(Ab + (size_t)(m0 + row) * KDIM + ss * 8, &As[0][(row * 8 + su) * 8]);
        gload16(Bw + (size_t)(n0 + row) * KDIM + ss * 8, &Bs[0][(row * 8 + su) * 8]);
    }
    asm volatile("s_waitcnt vmcnt(0)" ::: "memory");
    __builtin_amdgcn_s_barrier();

    int cur = 0;
#pragma unroll 1
    for (int s = 0; s < NSTEP; ++s) {
        // ---- issue next tile's staging into buf^1 (latency hides under MFMA)
        if (s + 1 < NSTEP) {
            int kt = (s + 1) * 64;
#pragma unroll
            for (int cc = 0; cc < 4; ++cc) {
                int row = cc * 32 + srow;
                int ss = su ^ (row & 7);
                gload16(Ab + (size_t)(m0 + row) * KDIM + kt + ss * 8,
                        &As[cur ^ 1][(row * 8 + su) * 8]);
                gload16(Bw + (size_t)(n0 + row) * KDIM + kt + ss * 8,
                        &Bs[cur ^ 1][(row * 8 + su) * 8]);
            }
        }

        // ---- compute current buffer ----
#pragma unroll
        for (int h = 0; h < 2; ++h) {
            bf16x8 af[4], bv[4];
#pragma unroll
            for (int mi = 0; mi < 4; ++mi) {
                int r = wr * 64 + mi * 16 + li;
                af[mi] = *(const bf16x8*)&As[cur][r * 64 + (((h * 4 + g) ^ (r & 7)) << 3)];
            }
#pragma unroll
            for (int ni = 0; ni < 4; ++ni) {
                int r = wc * 64 + ni * 16 + li;
                bv[ni] = *(const bf16x8*)&Bs[cur][r * 64 + (((h * 4 + g) ^ (r & 7)) << 3)];
            }
#pragma unroll
            for (int mi = 0; mi < 4; ++mi)
#pragma unroll
                for (int ni = 0; ni < 4; ++ni)
                    acc[mi][ni] = __builtin_amdgcn_mfma_f32_16x16x32_bf16(
                        af[mi], bv[ni], acc[mi][ni], 0, 0, 0);
        }

        if (s + 1 < NSTEP) {
            // prefetch done + all waves' LDS reads of buf[cur] complete
            asm volatile("s_waitcnt vmcnt(0)" ::: "memory");
            __builtin_amdgcn_s_barrier();
            cur ^= 1;
        }
    }

    // ---- epilogue: transposed store D[m][n] -> dst[n][m] ----
#pragma unroll
    for (int ni = 0; ni < 4; ++ni) {
        int n = n0 + wc * 64 + ni * 16 + li;
        if constexpr (MODE == 0) {
            float bias = (n < 256) ? b0[n] : b1[n - 256];
            u16* dst = (u16*)((n < 256) ? out0_ : out1_) + ((size_t)bz * 256 + (n & 255)) * HWN;
#pragma unroll
            for (int mi = 0; mi < 4; ++mi) {
                int m = m0 + wr * 64 + mi * 16 + (g << 2);
                f32x4 v = acc[mi][ni];
                float e0 = fmaxf(v.x + bias, 0.f), e1 = fmaxf(v.y + bias, 0.f);
                float e2 = fmaxf(v.z + bias, 0.f), e3 = fmaxf(v.w + bias, 0.f);
                uint2 pk = {bf16_pack(e0, e1), bf16_pack(e2, e3)};
                *(uint2*)(dst + m) = pk;
            }
        } else {
            float bias = b0[n];
            float* dst = (float*)out0_ + ((size_t)bz * 512 + n) * HWN;
            const float* res = resid + ((size_t)bz * 512 + n) * HWN;
#pragma unroll
            for (int mi = 0; mi < 4; ++mi) {
                int m = m0 + wr * 64 + mi * 16 + (g << 2);
                f32x4 v = acc[mi][ni];
                float4 rx = *(const float4*)(res + m);
                float4 o = {v.x + bias + rx.x, v.y + bias + rx.y,
                            v.z + bias + rx.z, v.w + bias + rx.w};
                *(float4*)(dst + m) = o;
            }
        }
    }
}

// ---------------------------------------------------------------------------
// SPP pooling, fp32 input (x) -> xp [B][512][110] fp32
// ---------------------------------------------------------------------------
__global__ __launch_bounds__(256) void pool_x_kernel(
    const float* __restrict__ in, float* __restrict__ out)
{
    __shared__ float ps[576];
    const int plane = blockIdx.x;
    const float* p = in + (size_t)plane * HWN;
    const int t = threadIdx.x;

    for (int i = t; i < 576; i += 256) {
        int bh = i / 24, bw = i % 24;
        float s = 0.f;
#pragma unroll
        for (int r = 0; r < 4; ++r) {
            float4 v = *(const float4*)&p[(bh * 4 + r) * 96 + bw * 4];
            s += v.x + v.y + v.z + v.w;
        }
        ps[i] = s;
    }
    __syncthreads();

    if (t < KP) {
        float s = 0.f;
        if (t == 0) {
            for (int i = 0; i < 576; ++i) s += ps[i];
            s *= (1.0f / 9216.0f);
        } else if (t < 10) {
            int idx = t - 1, bi = idx / 3, bj = idx % 3;
            for (int r = 0; r < 8; ++r)
                for (int c = 0; c < 8; ++c)
                    s += ps[(bi * 8 + r) * 24 + bj * 8 + c];
            s *= (1.0f / 1024.0f);
        } else if (t < 46) {
            int idx = t - 10, bi = idx / 6, bj = idx % 6;
            for (int r = 0; r < 4; ++r)
                for (int c = 0; c < 4; ++c)
                    s += ps[(bi * 4 + r) * 24 + bj * 4 + c];
            s *= (1.0f / 256.0f);
        } else {
            int idx = t - 46, bi = idx / 8, bj = idx % 8;
            for (int r = 0; r < 3; ++r)
                for (int c = 0; c < 3; ++c)
                    s += ps[(bi * 3 + r) * 24 + bj * 3 + c];
            s *= (1.0f / 144.0f);
        }
        out[(size_t)plane * KP + t] = s;
    }
}

// ---------------------------------------------------------------------------
// SPP pooling, bf16 input (theta) -> tpT [B][128][256] bf16 transposed, padded
// ---------------------------------------------------------------------------
__global__ __launch_bounds__(256) void pool_t_kernel(
    const u16* __restrict__ in, u16* __restrict__ outT)
{
    __shared__ float ps[576];
    const int plane = blockIdx.x;
    const int b = plane >> 8, c = plane & 255;
    const u16* p = in + (size_t)plane * HWN;
    const int t = threadIdx.x;

    for (int i = t; i < 576; i += 256) {
        int bh = i / 24, bw = i % 24;
        float s = 0.f;
#pragma unroll
        for (int r = 0; r < 4; ++r) {
            ushort4 v = *(const ushort4*)&p[(bh * 4 + r) * 96 + bw * 4];
            s += b2f(v.x) + b2f(v.y) + b2f(v.z) + b2f(v.w);
        }
        ps[i] = s;
    }
    __syncthreads();

    if (t < 128) {
        float s = 0.f;
        if (t == 0) {
            for (int i = 0; i < 576; ++i) s += ps[i];
            s *= (1.0f / 9216.0f);
        } else if (t < 10) {
            int idx = t - 1, bi = idx / 3, bj = idx % 3;
            for (int r = 0; r < 8; ++r)
                for (int cc = 0; cc < 8; ++cc)
                    s += ps[(bi * 8 + r) * 24 + bj * 8 + cc];
            s *= (1.0f / 1024.0f);
        } else if (t < 46) {
            int idx = t - 10, bi = idx / 6, bj = idx % 6;
            for (int r = 0; r < 4; ++r)
                for (int cc = 0; cc < 4; ++cc)
                    s += ps[(bi * 4 + r) * 24 + bj * 4 + cc];
            s *= (1.0f / 256.0f);
        } else if (t < KP) {
            int idx = t - 46, bi = idx / 8, bj = idx % 8;
            for (int r = 0; r < 3; ++r)
                for (int cc = 0; cc < 3; ++cc)
                    s += ps[(bi * 3 + r) * 24 + bj * 3 + cc];
            s *= (1.0f / 144.0f);
        } else {
            s = 0.f;
        }
        outT[((size_t)b * 128 + t) * 256 + c] = (u16)bf16_1(s);
    }
}

// ---------------------------------------------------------------------------
// gamma_p k-minor: gp[b][c][k] bf16, k padded to 128 with zeros
// ---------------------------------------------------------------------------
__global__ __launch_bounds__(256) void gammap_kernel(
    const float* __restrict__ xp,
    const float* __restrict__ gw,
    const float* __restrict__ gb,
    u16* __restrict__ gp)
{
    const int k = blockIdx.x, b = blockIdx.y;
    const int t = threadIdx.x;
    if (k >= KP) {
        gp[((size_t)b * 256 + t) * 128 + k] = 0;
        return;
    }
    __shared__ float xc[512];
    xc[t]       = xp[((size_t)b * CIN + t) * KP + k];
    xc[t + 256] = xp[((size_t)b * CIN + t + 256) * KP + k];
    __syncthreads();

    float acc = gb[t];
    const float* wrow = gw + (size_t)t * CIN;
#pragma unroll 4
    for (int c = 0; c < CIN; c += 4) {
        float4 wv = *(const float4*)&wrow[c];
        acc = fmaf(wv.x, xc[c], acc);
        acc = fmaf(wv.y, xc[c + 1], acc);
        acc = fmaf(wv.z, xc[c + 2], acc);
        acc = fmaf(wv.w, xc[c + 3], acc);
    }
    gp[((size_t)b * 256 + t) * 128 + k] = (u16)bf16_1(acc);
}

// ---------------------------------------------------------------------------
// MFMA attention with m97-style LDS staging (round-6 version, unchanged).
// ---------------------------------------------------------------------------
__global__ __launch_bounds__(256) void attn_kernel(
    const u16* __restrict__ phi,   // [B][256][9216] bf16
    const u16* __restrict__ tpT,   // [B][128][256] bf16
    const u16* __restrict__ gp,    // [B][256][128] bf16
    u16* __restrict__ y2T)         // [B][9216 hw'][256 ci] bf16
{
    __shared__ __align__(16) u16 smem[32768];   // 64 KB
    u16* As = smem;
    u16* Bs = smem + 8192;
    char* Pb = (char*)(smem + 16384);

    const int t = threadIdx.x;
    const int w = t >> 6, l = t & 63;
    const int g = l >> 4, li = l & 15;
    const int b = blockIdx.y;
    const int rr = blockIdx.x >> 1;
    const int ci0 = (blockIdx.x & 1) << 7;

    const u16* phib = phi + (size_t)b * (OIN * HWN);
    const u16* tpb  = tpT + (size_t)b * (128 * 256);
    const u16* gpb  = gp  + (size_t)b * (256 * 128);

    const int srow = t >> 3;
    const int su = t & 7;

    f32x4 zero = {0.f, 0.f, 0.f, 0.f};
    f32x4 acc[2][8];
#pragma unroll
    for (int i = 0; i < 2; ++i)
#pragma unroll
        for (int j = 0; j < 8; ++j) acc[i][j] = zero;

    for (int kt = 0; kt < 256; kt += 64) {
#pragma unroll
        for (int cc = 0; cc < 4; ++cc) {
            int row = cc * 32 + srow;
            int ss = su ^ (row & 7);
            gload16(phib + (size_t)(ci0 + row) * HWN + rr * 256 + kt + ss * 8,
                    &As[(row * 8 + su) * 8]);
        }
#pragma unroll
        for (int cc = 0; cc < 4; ++cc) {
            int row = cc * 32 + srow;
            int ss = su ^ (row & 7);
            gload16(tpb + (size_t)row * 256 + kt + ss * 8,
                    &Bs[(row * 8 + su) * 8]);
        }
        __syncthreads();

#pragma unroll
        for (int h = 0; h < 2; ++h) {
            bf16x8 af[2], bfr[8];
#pragma unroll
            for (int mi = 0; mi < 2; ++mi) {
                int r = w * 32 + mi * 16 + li;
                af[mi] = *(const bf16x8*)&As[r * 64 + (((h * 4 + g) ^ (r & 7)) << 3)];
            }
#pragma unroll
            for (int ni = 0; ni < 8; ++ni) {
                int r = ni * 16 + li;
                bfr[ni] = *(const bf16x8*)&Bs[r * 64 + (((h * 4 + g) ^ (r & 7)) << 3)];
            }
#pragma unroll
            for (int mi = 0; mi < 2; ++mi)
#pragma unroll
                for (int ni = 0; ni < 8; ++ni)
                    acc[mi][ni] = __builtin_amdgcn_mfma_f32_16x16x32_bf16(
                        af[mi], bfr[ni], acc[mi][ni], 0, 0, 0);
        }
        __syncthreads();
    }

    bool vm[8];
#pragma unroll
    for (int ni = 0; ni < 8; ++ni) vm[ni] = (ni * 16 + li) < KP;

#pragma unroll
    for (int mi = 0; mi < 2; ++mi) {
#pragma unroll
        for (int r = 0; r < 4; ++r) {
            float mx = -1e30f;
#pragma unroll
            for (int ni = 0; ni < 8; ++ni)
                if (vm[ni]) mx = fmaxf(mx, acc[mi][ni][r] * SCL);
            mx = fmaxf(mx, __shfl_xor(mx, 1));
            mx = fmaxf(mx, __shfl_xor(mx, 2));
            mx = fmaxf(mx, __shfl_xor(mx, 4));
            mx = fmaxf(mx, __shfl_xor(mx, 8));
            float s = 0.f;
#pragma unroll
            for (int ni = 0; ni < 8; ++ni) {
                float e = vm[ni] ? __expf(acc[mi][ni][r] * SCL - mx) : 0.f;
                acc[mi][ni][r] = e;
                s += e;
            }
            s += __shfl_xor(s, 1);
            s += __shfl_xor(s, 2);
            s += __shfl_xor(s, 4);
            s += __shfl_xor(s, 8);
            float inv = 1.0f / s;
#pragma unroll
            for (int ni = 0; ni < 8; ++ni) acc[mi][ni][r] *= inv;
        }
#pragma unroll
        for (int ni = 0; ni < 8; ++ni)
#pragma unroll
            for (int r = 0; r < 4; ++r) {
                int row = w * 32 + mi * 16 + g * 4 + r;
                int col = ni * 16 + li;
                *(short*)(Pb + row * 256 + (((col >> 3) ^ (row & 7)) << 4) + ((col & 7) << 1)) =
                    (short)bf16_1(acc[mi][ni][r]);
            }
    }

    f32x4 acc2[2][16];
#pragma unroll
    for (int i = 0; i < 2; ++i)
#pragma unroll
        for (int j = 0; j < 16; ++j) acc2[i][j] = zero;

#pragma unroll 1
    for (int ks2 = 0; ks2 < 2; ++ks2) {
#pragma unroll
        for (int cc = 0; cc < 8; ++cc) {
            int row = cc * 32 + srow;
            int ss = su ^ (row & 7);
            gload16(gpb + (size_t)row * 128 + ks2 * 64 + ss * 8,
                    &smem[(row * 8 + su) * 8]);
        }
        __syncthreads();

#pragma unroll
        for (int h = 0; h < 2; ++h) {
            bf16x8 a2[2];
#pragma unroll
            for (int mi = 0; mi < 2; ++mi) {
                int prow = w * 32 + mi * 16 + li;
                int s = ks2 * 8 + h * 4 + g;
                a2[mi] = *(const bf16x8*)(Pb + prow * 256 + ((s ^ (prow & 7)) << 4));
            }
#pragma unroll
            for (int cf = 0; cf < 16; ++cf) {
                int crow = cf * 16 + li;
                bf16x8 bv = *(const bf16x8*)&smem[crow * 64 + (((h * 4 + g) ^ (crow & 7)) << 3)];
#pragma unroll
                for (int mi = 0; mi < 2; ++mi)
                    acc2[mi][cf] = __builtin_amdgcn_mfma_f32_16x16x32_bf16(
                        a2[mi], bv, acc2[mi][cf], 0, 0, 0);
            }
        }
        __syncthreads();
    }

#pragma unroll
    for (int mi = 0; mi < 2; ++mi)
#pragma unroll
        for (int cf = 0; cf < 16; ++cf) {
            int c = cf * 16 + li;
            int cib = w * 32 + mi * 16 + g * 4;
            int e0 = c * 128 + (cib ^ (li << 3));
            unsigned d0 = bf16_pack(acc2[mi][cf][0], acc2[mi][cf][1]);
            unsigned d1 = bf16_pack(acc2[mi][cf][2], acc2[mi][cf][3]);
            *(unsigned*)((char*)smem + (size_t)e0 * 2) = d0;
            *(unsigned*)((char*)smem + (size_t)e0 * 2 + 4) = d1;
        }

    __syncthreads();

    {
        u16* yb = y2T + ((size_t)b * HWN + rr * 256) * 256 + ci0;
#pragma unroll
        for (int j = 0; j < 16; ++j) {
            int c = (t >> 4) + (j << 4);
            int e = c * 128 + (((t & 15) ^ (t >> 4)) << 3);
            uint4 v = *(const uint4*)((char*)smem + (size_t)e * 2);
            *(uint4*)(yb + (size_t)c * 256 + (t & 15) * 8) = v;
        }
    }
}

extern "C" void kernel_launch(void* const* d_in, const int* in_sizes, int n_in,
                              void* d_out, int out_size, void* d_ws, size_t ws_size,
                              hipStream_t stream)
{
    const float* x       = (const float*)d_in[0];
    const float* phi_w   = (const float*)d_in[1];
    const float* phi_b   = (const float*)d_in[2];
    const float* theta_w = (const float*)d_in[3];
    const float* theta_b = (const float*)d_in[4];
    const float* gamma_w = (const float*)d_in[5];
    const float* gamma_b = (const float*)d_in[6];
    const float* W_w     = (const float*)d_in[7];
    const float* W_b     = (const float*)d_in[8];
    float* out = (float*)d_out;

    char* p = (char*)d_ws;
    u16* xT     = (u16*)p;  p += (size_t)NB * HWN * CIN * 2;   // 75.5 MB
    u16* phi_bf = (u16*)p;  p += (size_t)NB * OIN * HWN * 2;   // 37.7 MB
    u16* th_y2  = (u16*)p;  p += (size_t)NB * OIN * HWN * 2;   // 37.7 MB (theta, then y2T)
    float* xp   = (float*)p; p += (size_t)NB * CIN * KP * 4;
    u16* tpT    = (u16*)p;  p += (size_t)NB * 128 * 256 * 2;
    u16* gp     = (u16*)p;  p += (size_t)NB * 256 * 128 * 2;
    u16* Wcat   = (u16*)p;  p += 512 * 512 * 2;
    u16* Wwb    = (u16*)p;  p += 512 * 256 * 2;

    castw_kernel<<<1536, 256, 0, stream>>>(phi_w, theta_w, W_w, Wcat, Wwb);
    castx_kernel<<<dim3(144, 8, NB), 256, 0, stream>>>(x, xT);
    gemm_kernel<512, 0><<<dim3(72 * 4 * NB), 256, 0, stream>>>(
        xT, Wcat, phi_b, theta_b, nullptr, phi_bf, th_y2);
    pool_x_kernel<<<dim3(NB * CIN), 256, 0, stream>>>(x, xp);
    pool_t_kernel<<<dim3(NB * OIN), 256, 0, stream>>>(th_y2, tpT);
    gammap_kernel<<<dim3(128, NB), 256, 0, stream>>>(xp, gamma_w, gamma_b, gp);
    attn_kernel<<<dim3(72, NB), 256, 0, stream>>>(phi_bf, tpT, gp, th_y2);
    gemm_kernel<256, 1><<<dim3(72 * 4 * NB), 256, 0, stream>>>(
        th_y2, Wwb, W_b, nullptr, x, out, nullptr);
}

// Round 8
// 368.188 us; speedup vs baseline: 1.0009x; 1.0009x over previous
//
#include <hip/hip_runtime.h>

#define NB 8
#define CIN 512
#define OIN 256
#define HWN 9216
#define KP 110
#define SCL 0.10206207261596577f  // 9216^(-0.25)

typedef __attribute__((ext_vector_type(8))) short bf16x8;
typedef __attribute__((ext_vector_type(4))) float f32x4;
typedef unsigned short u16;

__device__ inline unsigned bf16_1(float a) {
    unsigned u = __builtin_bit_cast(unsigned, a);
    return (u + 0x7fffu + ((u >> 16) & 1u)) >> 16;
}
__device__ inline unsigned bf16_pack(float a, float b) {
    return bf16_1(a) | (bf16_1(b) << 16);
}
__device__ inline float b2f(u16 u) {
    return __builtin_bit_cast(float, ((unsigned)u) << 16);
}

__device__ __forceinline__ void gload16(const u16* g, u16* l) {
    __builtin_amdgcn_global_load_lds(
        (const __attribute__((address_space(1))) unsigned int*)g,
        (__attribute__((address_space(3))) unsigned int*)l, 16, 0, 0);
}

// ---------------------------------------------------------------------------
// Weight cast: phi_w+theta_w -> Wcat bf16 [512][512]; W_w -> Wwb bf16 [512][256]
// ---------------------------------------------------------------------------
__global__ __launch_bounds__(256) void castw_kernel(
    const float* __restrict__ phi_w, const float* __restrict__ theta_w,
    const float* __restrict__ Ww,
    u16* __restrict__ Wcat, u16* __restrict__ Wwb)
{
    int i = blockIdx.x * 256 + threadIdx.x;
    if (i < 262144) {
        float v = (i < 131072) ? phi_w[i] : theta_w[i - 131072];
        Wcat[i] = (u16)bf16_1(v);
    } else {
        int j = i - 262144;
        Wwb[j] = (u16)bf16_1(Ww[j]);
    }
}

// ---------------------------------------------------------------------------
// castx: x fp32 [b][512 c][9216 hw] -> xT bf16 [b][9216 hw][512 c]
// ---------------------------------------------------------------------------
__global__ __launch_bounds__(256) void castx_kernel(
    const float* __restrict__ x, u16* __restrict__ xT)
{
    const int t = threadIdx.x;
    const int tx = t & 15, ty = t >> 4;
    const int b = blockIdx.z;
    const int c0 = blockIdx.y * 64;
    const int hw0 = blockIdx.x * 64;

    const float* xb = x + ((size_t)b * CIN + c0 + ty * 4) * HWN + hw0 + tx * 4;
    float4 v[4];
#pragma unroll
    for (int q = 0; q < 4; ++q)
        v[q] = *(const float4*)(xb + (size_t)q * HWN);

    u16* dst = xT + ((size_t)b * HWN + hw0 + tx * 4) * CIN + c0 + ty * 4;
    const float* f = (const float*)v;
#pragma unroll
    for (int p = 0; p < 4; ++p) {
        uint2 o = {bf16_pack(f[0 * 4 + p], f[1 * 4 + p]),
                   bf16_pack(f[2 * 4 + p], f[3 * 4 + p])};
        *(uint2*)(dst + (size_t)p * CIN) = o;
    }
}

// ---------------------------------------------------------------------------
// MFMA GEMM, 4-deep pipelined (T3+T4: counted vmcnt, loads span barriers):
//   D[m=hw][n=o] = sum_k A[m][k] * Bw[n][k]   (per batch)
//   BK=32, 4 LDS buffers (64 KB), prefetch 3 steps ahead, vmcnt(8) steady.
//   Per step: vmcnt -> barrier -> issue s+3 -> 8 ds_read_b128 + 16 MFMA.
//   XCD swizzle: 288-block chunk per XCD = one batch; by-minor so the 4
//   n-blocks sharing an A-panel are consecutive (A L2-resident).
// ---------------------------------------------------------------------------
template<int KDIM, int MODE>
__global__ __launch_bounds__(256) void gemm_kernel(
    const u16* __restrict__ A,
    const u16* __restrict__ Bw,
    const float* __restrict__ b0, const float* __restrict__ b1,
    const float* __restrict__ resid,
    void* __restrict__ out0_, void* __restrict__ out1_)
{
    __shared__ u16 As[4][128 * 32];
    __shared__ u16 Bs[4][128 * 32];

    constexpr int NSTEP = KDIM / 32;
    constexpr int NWG = 72 * 4 * NB;

    // bijective XCD swizzle, by-minor within each XCD chunk
    const int id = blockIdx.x;
    const int swz = (id & 7) * (NWG / 8) + (id >> 3);
    const int u = swz % 288;
    const int bz = swz / 288;
    const int by = u & 3;
    const int bx = u >> 2;

    const int t = threadIdx.x;
    const int m0 = bx * 128;
    const int n0 = by * 128;
    const int w = t >> 6, l = t & 63;
    const int wr = w >> 1, wc = w & 1;
    const int g = l >> 4, li = l & 15;

    const u16* Ab = A + (size_t)bz * HWN * KDIM + (size_t)m0 * KDIM;
    const u16* Bb = Bw + (size_t)n0 * KDIM;

    f32x4 zero = {0.f, 0.f, 0.f, 0.f};
    f32x4 acc[4][4];
#pragma unroll
    for (int i = 0; i < 4; ++i)
#pragma unroll
        for (int j = 0; j < 4; ++j) acc[i][j] = zero;

    // stage one K=32 step into buffer buf.
    // chunk c in [0,512): row=c>>2, slot=c&3; global slot = slot ^ sw(row);
    // LDS linear at c*16B (lane-contiguous per instruction, m104-safe).
    auto stage = [&](int step, int buf) {
#pragma unroll
        for (int j = 0; j < 2; ++j) {
            int c = j * 256 + t;
            int row = c >> 2, slot = c & 3;
            int ss = slot ^ ((row ^ (row >> 2)) & 3);
            gload16(Ab + (size_t)row * KDIM + step * 32 + ss * 8, &As[buf][c * 8]);
        }
#pragma unroll
        for (int j = 0; j < 2; ++j) {
            int c = j * 256 + t;
            int row = c >> 2, slot = c & 3;
            int ss = slot ^ ((row ^ (row >> 2)) & 3);
            gload16(Bb + (size_t)row * KDIM + step * 32 + ss * 8, &Bs[buf][c * 8]);
        }
    };

    // prologue: 3 steps in flight (12 loads/wave)
    stage(0, 0);
    stage(1, 1);
    stage(2, 2);

#pragma unroll 1
    for (int s = 0; s < NSTEP; ++s) {
        if (s + 2 < NSTEP) {
            // outstanding = 12 (steps s,s+1,s+2); wait oldest 4 (step s)
            asm volatile("s_waitcnt vmcnt(8)" ::: "memory");
        } else {
            asm volatile("s_waitcnt vmcnt(0)" ::: "memory");
        }
        __builtin_amdgcn_s_barrier();        // all waves' step-s loads landed;
        __builtin_amdgcn_sched_barrier(0);   // + all waves done reading buf[(s-1)&3]

        if (s + 3 < NSTEP) stage(s + 3, (s + 3) & 3);

        const int cb = s & 3;
        bf16x8 af[4], bv[4];
#pragma unroll
        for (int mi = 0; mi < 4; ++mi) {
            int r = wr * 64 + mi * 16 + li;
            int sl = g ^ ((r ^ (r >> 2)) & 3);
            af[mi] = *(const bf16x8*)&As[cb][r * 32 + sl * 8];
        }
#pragma unroll
        for (int ni = 0; ni < 4; ++ni) {
            int r = wc * 64 + ni * 16 + li;
            int sl = g ^ ((r ^ (r >> 2)) & 3);
            bv[ni] = *(const bf16x8*)&Bs[cb][r * 32 + sl * 8];
        }
#pragma unroll
        for (int mi = 0; mi < 4; ++mi)
#pragma unroll
            for (int ni = 0; ni < 4; ++ni)
                acc[mi][ni] = __builtin_amdgcn_mfma_f32_16x16x32_bf16(
                    af[mi], bv[ni], acc[mi][ni], 0, 0, 0);
    }

    // ---- epilogue: transposed store D[m][n] -> dst[n][m] ----
#pragma unroll
    for (int ni = 0; ni < 4; ++ni) {
        int n = n0 + wc * 64 + ni * 16 + li;
        if constexpr (MODE == 0) {
            float bias = (n < 256) ? b0[n] : b1[n - 256];
            u16* dst = (u16*)((n < 256) ? out0_ : out1_) + ((size_t)bz * 256 + (n & 255)) * HWN;
#pragma unroll
            for (int mi = 0; mi < 4; ++mi) {
                int m = m0 + wr * 64 + mi * 16 + (g << 2);
                f32x4 v = acc[mi][ni];
                float e0 = fmaxf(v.x + bias, 0.f), e1 = fmaxf(v.y + bias, 0.f);
                float e2 = fmaxf(v.z + bias, 0.f), e3 = fmaxf(v.w + bias, 0.f);
                uint2 pk = {bf16_pack(e0, e1), bf16_pack(e2, e3)};
                *(uint2*)(dst + m) = pk;
            }
        } else {
            float bias = b0[n];
            float* dst = (float*)out0_ + ((size_t)bz * 512 + n) * HWN;
            const float* res = resid + ((size_t)bz * 512 + n) * HWN;
#pragma unroll
            for (int mi = 0; mi < 4; ++mi) {
                int m = m0 + wr * 64 + mi * 16 + (g << 2);
                f32x4 v = acc[mi][ni];
                float4 rx = *(const float4*)(res + m);
                float4 o = {v.x + bias + rx.x, v.y + bias + rx.y,
                            v.z + bias + rx.z, v.w + bias + rx.w};
                *(float4*)(dst + m) = o;
            }
        }
    }
}

// ---------------------------------------------------------------------------
// SPP pooling, fp32 input (x) -> xp [B][512][110] fp32
// ---------------------------------------------------------------------------
__global__ __launch_bounds__(256) void pool_x_kernel(
    const float* __restrict__ in, float* __restrict__ out)
{
    __shared__ float ps[576];
    const int plane = blockIdx.x;
    const float* p = in + (size_t)plane * HWN;
    const int t = threadIdx.x;

    for (int i = t; i < 576; i += 256) {
        int bh = i / 24, bw = i % 24;
        float s = 0.f;
#pragma unroll
        for (int r = 0; r < 4; ++r) {
            float4 v = *(const float4*)&p[(bh * 4 + r) * 96 + bw * 4];
            s += v.x + v.y + v.z + v.w;
        }
        ps[i] = s;
    }
    __syncthreads();

    if (t < KP) {
        float s = 0.f;
        if (t == 0) {
            for (int i = 0; i < 576; ++i) s += ps[i];
            s *= (1.0f / 9216.0f);
        } else if (t < 10) {
            int idx = t - 1, bi = idx / 3, bj = idx % 3;
            for (int r = 0; r < 8; ++r)
                for (int c = 0; c < 8; ++c)
                    s += ps[(bi * 8 + r) * 24 + bj * 8 + c];
            s *= (1.0f / 1024.0f);
        } else if (t < 46) {
            int idx = t - 10, bi = idx / 6, bj = idx % 6;
            for (int r = 0; r < 4; ++r)
                for (int c = 0; c < 4; ++c)
                    s += ps[(bi * 4 + r) * 24 + bj * 4 + c];
            s *= (1.0f / 256.0f);
        } else {
            int idx = t - 46, bi = idx / 8, bj = idx % 8;
            for (int r = 0; r < 3; ++r)
                for (int c = 0; c < 3; ++c)
                    s += ps[(bi * 3 + r) * 24 + bj * 3 + c];
            s *= (1.0f / 144.0f);
        }
        out[(size_t)plane * KP + t] = s;
    }
}

// ---------------------------------------------------------------------------
// SPP pooling, bf16 input (theta) -> tpT [B][128][256] bf16 transposed, padded
// ---------------------------------------------------------------------------
__global__ __launch_bounds__(256) void pool_t_kernel(
    const u16* __restrict__ in, u16* __restrict__ outT)
{
    __shared__ float ps[576];
    const int plane = blockIdx.x;
    const int b = plane >> 8, c = plane & 255;
    const u16* p = in + (size_t)plane * HWN;
    const int t = threadIdx.x;

    for (int i = t; i < 576; i += 256) {
        int bh = i / 24, bw = i % 24;
        float s = 0.f;
#pragma unroll
        for (int r = 0; r < 4; ++r) {
            ushort4 v = *(const ushort4*)&p[(bh * 4 + r) * 96 + bw * 4];
            s += b2f(v.x) + b2f(v.y) + b2f(v.z) + b2f(v.w);
        }
        ps[i] = s;
    }
    __syncthreads();

    if (t < 128) {
        float s = 0.f;
        if (t == 0) {
            for (int i = 0; i < 576; ++i) s += ps[i];
            s *= (1.0f / 9216.0f);
        } else if (t < 10) {
            int idx = t - 1, bi = idx / 3, bj = idx % 3;
            for (int r = 0; r < 8; ++r)
                for (int cc = 0; cc < 8; ++cc)
                    s += ps[(bi * 8 + r) * 24 + bj * 8 + cc];
            s *= (1.0f / 1024.0f);
        } else if (t < 46) {
            int idx = t - 10, bi = idx / 6, bj = idx % 6;
            for (int r = 0; r < 4; ++r)
                for (int cc = 0; cc < 4; ++cc)
                    s += ps[(bi * 4 + r) * 24 + bj * 4 + cc];
            s *= (1.0f / 256.0f);
        } else if (t < KP) {
            int idx = t - 46, bi = idx / 8, bj = idx % 8;
            for (int r = 0; r < 3; ++r)
                for (int cc = 0; cc < 3; ++cc)
                    s += ps[(bi * 3 + r) * 24 + bj * 3 + cc];
            s *= (1.0f / 144.0f);
        } else {
            s = 0.f;
        }
        outT[((size_t)b * 128 + t) * 256 + c] = (u16)bf16_1(s);
    }
}

// ---------------------------------------------------------------------------
// gamma_p k-minor: gp[b][c][k] bf16, k padded to 128 with zeros
// ---------------------------------------------------------------------------
__global__ __launch_bounds__(256) void gammap_kernel(
    const float* __restrict__ xp,
    const float* __restrict__ gw,
    const float* __restrict__ gb,
    u16* __restrict__ gp)
{
    const int k = blockIdx.x, b = blockIdx.y;
    const int t = threadIdx.x;
    if (k >= KP) {
        gp[((size_t)b * 256 + t) * 128 + k] = 0;
        return;
    }
    __shared__ float xc[512];
    xc[t]       = xp[((size_t)b * CIN + t) * KP + k];
    xc[t + 256] = xp[((size_t)b * CIN + t + 256) * KP + k];
    __syncthreads();

    float acc = gb[t];
    const float* wrow = gw + (size_t)t * CIN;
#pragma unroll 4
    for (int c = 0; c < CIN; c += 4) {
        float4 wv = *(const float4*)&wrow[c];
        acc = fmaf(wv.x, xc[c], acc);
        acc = fmaf(wv.y, xc[c + 1], acc);
        acc = fmaf(wv.z, xc[c + 2], acc);
        acc = fmaf(wv.w, xc[c + 3], acc);
    }
    gp[((size_t)b * 256 + t) * 128 + k] = (u16)bf16_1(acc);
}

// ---------------------------------------------------------------------------
// MFMA attention with m97-style LDS staging (unchanged from round 6).
// ---------------------------------------------------------------------------
__global__ __launch_bounds__(256) void attn_kernel(
    const u16* __restrict__ phi,   // [B][256][9216] bf16
    const u16* __restrict__ tpT,   // [B][128][256] bf16
    const u16* __restrict__ gp,    // [B][256][128] bf16
    u16* __restrict__ y2T)         // [B][9216 hw'][256 ci] bf16
{
    __shared__ __align__(16) u16 smem[32768];   // 64 KB
    u16* As = smem;
    u16* Bs = smem + 8192;
    char* Pb = (char*)(smem + 16384);

    const int t = threadIdx.x;
    const int w = t >> 6, l = t & 63;
    const int g = l >> 4, li = l & 15;
    const int b = blockIdx.y;
    const int rr = blockIdx.x >> 1;
    const int ci0 = (blockIdx.x & 1) << 7;

    const u16* phib = phi + (size_t)b * (OIN * HWN);
    const u16* tpb  = tpT + (size_t)b * (128 * 256);
    const u16* gpb  = gp  + (size_t)b * (256 * 128);

    const int srow = t >> 3;
    const int su = t & 7;

    f32x4 zero = {0.f, 0.f, 0.f, 0.f};
    f32x4 acc[2][8];
#pragma unroll
    for (int i = 0; i < 2; ++i)
#pragma unroll
        for (int j = 0; j < 8; ++j) acc[i][j] = zero;

    for (int kt = 0; kt < 256; kt += 64) {
#pragma unroll
        for (int cc = 0; cc < 4; ++cc) {
            int row = cc * 32 + srow;
            int ss = su ^ (row & 7);
            gload16(phib + (size_t)(ci0 + row) * HWN + rr * 256 + kt + ss * 8,
                    &As[(row * 8 + su) * 8]);
        }
#pragma unroll
        for (int cc = 0; cc < 4; ++cc) {
            int row = cc * 32 + srow;
            int ss = su ^ (row & 7);
            gload16(tpb + (size_t)row * 256 + kt + ss * 8,
                    &Bs[(row * 8 + su) * 8]);
        }
        __syncthreads();

#pragma unroll
        for (int h = 0; h < 2; ++h) {
            bf16x8 af[2], bfr[8];
#pragma unroll
            for (int mi = 0; mi < 2; ++mi) {
                int r = w * 32 + mi * 16 + li;
                af[mi] = *(const bf16x8*)&As[r * 64 + (((h * 4 + g) ^ (r & 7)) << 3)];
            }
#pragma unroll
            for (int ni = 0; ni < 8; ++ni) {
                int r = ni * 16 + li;
                bfr[ni] = *(const bf16x8*)&Bs[r * 64 + (((h * 4 + g) ^ (r & 7)) << 3)];
            }
#pragma unroll
            for (int mi = 0; mi < 2; ++mi)
#pragma unroll
                for (int ni = 0; ni < 8; ++ni)
                    acc[mi][ni] = __builtin_amdgcn_mfma_f32_16x16x32_bf16(
                        af[mi], bfr[ni], acc[mi][ni], 0, 0, 0);
        }
        __syncthreads();
    }

    bool vm[8];
#pragma unroll
    for (int ni = 0; ni < 8; ++ni) vm[ni] = (ni * 16 + li) < KP;

#pragma unroll
    for (int mi = 0; mi < 2; ++mi) {
#pragma unroll
        for (int r = 0; r < 4; ++r) {
            float mx = -1e30f;
#pragma unroll
            for (int ni = 0; ni < 8; ++ni)
                if (vm[ni]) mx = fmaxf(mx, acc[mi][ni][r] * SCL);
            mx = fmaxf(mx, __shfl_xor(mx, 1));
            mx = fmaxf(mx, __shfl_xor(mx, 2));
            mx = fmaxf(mx, __shfl_xor(mx, 4));
            mx = fmaxf(mx, __shfl_xor(mx, 8));
            float s = 0.f;
#pragma unroll
            for (int ni = 0; ni < 8; ++ni) {
                float e = vm[ni] ? __expf(acc[mi][ni][r] * SCL - mx) : 0.f;
                acc[mi][ni][r] = e;
                s += e;
            }
            s += __shfl_xor(s, 1);
            s += __shfl_xor(s, 2);
            s += __shfl_xor(s, 4);
            s += __shfl_xor(s, 8);
            float inv = 1.0f / s;
#pragma unroll
            for (int ni = 0; ni < 8; ++ni) acc[mi][ni][r] *= inv;
        }
#pragma unroll
        for (int ni = 0; ni < 8; ++ni)
#pragma unroll
            for (int r = 0; r < 4; ++r) {
                int row = w * 32 + mi * 16 + g * 4 + r;
                int col = ni * 16 + li;
                *(short*)(Pb + row * 256 + (((col >> 3) ^ (row & 7)) << 4) + ((col & 7) << 1)) =
                    (short)bf16_1(acc[mi][ni][r]);
            }
    }

    f32x4 acc2[2][16];
#pragma unroll
    for (int i = 0; i < 2; ++i)
#pragma unroll
        for (int j = 0; j < 16; ++j) acc2[i][j] = zero;

#pragma unroll 1
    for (int ks2 = 0; ks2 < 2; ++ks2) {
#pragma unroll
        for (int cc = 0; cc < 8; ++cc) {
            int row = cc * 32 + srow;
            int ss = su ^ (row & 7);
            gload16(gpb + (size_t)row * 128 + ks2 * 64 + ss * 8,
                    &smem[(row * 8 + su) * 8]);
        }
        __syncthreads();

#pragma unroll
        for (int h = 0; h < 2; ++h) {
            bf16x8 a2[2];
#pragma unroll
            for (int mi = 0; mi < 2; ++mi) {
                int prow = w * 32 + mi * 16 + li;
                int s = ks2 * 8 + h * 4 + g;
                a2[mi] = *(const bf16x8*)(Pb + prow * 256 + ((s ^ (prow & 7)) << 4));
            }
#pragma unroll
            for (int cf = 0; cf < 16; ++cf) {
                int crow = cf * 16 + li;
                bf16x8 bv = *(const bf16x8*)&smem[crow * 64 + (((h * 4 + g) ^ (crow & 7)) << 3)];
#pragma unroll
                for (int mi = 0; mi < 2; ++mi)
                    acc2[mi][cf] = __builtin_amdgcn_mfma_f32_16x16x32_bf16(
                        a2[mi], bv, acc2[mi][cf], 0, 0, 0);
            }
        }
        __syncthreads();
    }

#pragma unroll
    for (int mi = 0; mi < 2; ++mi)
#pragma unroll
        for (int cf = 0; cf < 16; ++cf) {
            int c = cf * 16 + li;
            int cib = w * 32 + mi * 16 + g * 4;
            int e0 = c * 128 + (cib ^ (li << 3));
            unsigned d0 = bf16_pack(acc2[mi][cf][0], acc2[mi][cf][1]);
            unsigned d1 = bf16_pack(acc2[mi][cf][2], acc2[mi][cf][3]);
            *(unsigned*)((char*)smem + (size_t)e0 * 2) = d0;
            *(unsigned*)((char*)smem + (size_t)e0 * 2 + 4) = d1;
        }

    __syncthreads();

    {
        u16* yb = y2T + ((size_t)b * HWN + rr * 256) * 256 + ci0;
#pragma unroll
        for (int j = 0; j < 16; ++j) {
            int c = (t >> 4) + (j << 4);
            int e = c * 128 + (((t & 15) ^ (t >> 4)) << 3);
            uint4 v = *(const uint4*)((char*)smem + (size_t)e * 2);
            *(uint4*)(yb + (size_t)c * 256 + (t & 15) * 8) = v;
        }
    }
}

extern "C" void kernel_launch(void* const* d_in, const int* in_sizes, int n_in,
                              void* d_out, int out_size, void* d_ws, size_t ws_size,
                              hipStream_t stream)
{
    const float* x       = (const float*)d_in[0];
    const float* phi_w   = (const float*)d_in[1];
    const float* phi_b   = (const float*)d_in[2];
    const float* theta_w = (const float*)d_in[3];
    const float* theta_b = (const float*)d_in[4];
    const float* gamma_w = (const float*)d_in[5];
    const float* gamma_b = (const float*)d_in[6];
    const float* W_w     = (const float*)d_in[7];
    const float* W_b     = (const float*)d_in[8];
    float* out = (float*)d_out;

    char* p = (char*)d_ws;
    u16* xT     = (u16*)p;  p += (size_t)NB * HWN * CIN * 2;   // 75.5 MB
    u16* phi_bf = (u16*)p;  p += (size_t)NB * OIN * HWN * 2;   // 37.7 MB
    u16* th_y2  = (u16*)p;  p += (size_t)NB * OIN * HWN * 2;   // 37.7 MB (theta, then y2T)
    float* xp   = (float*)p; p += (size_t)NB * CIN * KP * 4;
    u16* tpT    = (u16*)p;  p += (size_t)NB * 128 * 256 * 2;
    u16* gp     = (u16*)p;  p += (size_t)NB * 256 * 128 * 2;
    u16* Wcat   = (u16*)p;  p += 512 * 512 * 2;
    u16* Wwb    = (u16*)p;  p += 512 * 256 * 2;

    castw_kernel<<<1536, 256, 0, stream>>>(phi_w, theta_w, W_w, Wcat, Wwb);
    castx_kernel<<<dim3(144, 8, NB), 256, 0, stream>>>(x, xT);
    gemm_kernel<512, 0><<<dim3(72 * 4 * NB), 256, 0, stream>>>(
        xT, Wcat, phi_b, theta_b, nullptr, phi_bf, th_y2);
    pool_x_kernel<<<dim3(NB * CIN), 256, 0, stream>>>(x, xp);
    pool_t_kernel<<<dim3(NB * OIN), 256, 0, stream>>>(th_y2, tpT);
    gammap_kernel<<<dim3(128, NB), 256, 0, stream>>>(xp, gamma_w, gamma_b, gp);
    attn_kernel<<<dim3(72, NB), 256, 0, stream>>>(phi_bf, tpT, gp, th_y2);
    gemm_kernel<256, 1><<<dim3(72 * 4 * NB), 256, 0, stream>>>(
        th_y2, Wwb, W_b, nullptr, x, out, nullptr);
}

// Round 9
// 348.980 us; speedup vs baseline: 1.0559x; 1.0550x over previous
//
#include <hip/hip_runtime.h>

#define NB 8
#define CIN 512
#define OIN 256
#define HWN 9216
#define KP 110
#define SCL 0.10206207261596577f  // 9216^(-0.25)

typedef __attribute__((ext_vector_type(8))) short bf16x8;
typedef __attribute__((ext_vector_type(4))) float f32x4;
typedef unsigned short u16;

__device__ inline unsigned bf16_1(float a) {
    unsigned u = __builtin_bit_cast(unsigned, a);
    return (u + 0x7fffu + ((u >> 16) & 1u)) >> 16;
}
__device__ inline unsigned bf16_pack(float a, float b) {
    return bf16_1(a) | (bf16_1(b) << 16);
}
__device__ inline float b2f(u16 u) {
    return __builtin_bit_cast(float, ((unsigned)u) << 16);
}

__device__ __forceinline__ void gload16(const u16* g, u16* l) {
    __builtin_amdgcn_global_load_lds(
        (const __attribute__((address_space(1))) unsigned int*)g,
        (__attribute__((address_space(3))) unsigned int*)l, 16, 0, 0);
}

// ---------------------------------------------------------------------------
// Weight cast: phi_w+theta_w -> Wcat bf16 [512][512]; W_w -> Wwb bf16 [512][256]
// ---------------------------------------------------------------------------
__global__ __launch_bounds__(256) void castw_kernel(
    const float* __restrict__ phi_w, const float* __restrict__ theta_w,
    const float* __restrict__ Ww,
    u16* __restrict__ Wcat, u16* __restrict__ Wwb)
{
    int i = blockIdx.x * 256 + threadIdx.x;
    if (i < 262144) {
        float v = (i < 131072) ? phi_w[i] : theta_w[i - 131072];
        Wcat[i] = (u16)bf16_1(v);
    } else {
        int j = i - 262144;
        Wwb[j] = (u16)bf16_1(Ww[j]);
    }
}

// ---------------------------------------------------------------------------
// castx: x fp32 [b][512 c][9216 hw] -> xT bf16 [b][9216 hw][512 c]
// ---------------------------------------------------------------------------
__global__ __launch_bounds__(256) void castx_kernel(
    const float* __restrict__ x, u16* __restrict__ xT)
{
    const int t = threadIdx.x;
    const int tx = t & 15, ty = t >> 4;
    const int b = blockIdx.z;
    const int c0 = blockIdx.y * 64;
    const int hw0 = blockIdx.x * 64;

    const float* xb = x + ((size_t)b * CIN + c0 + ty * 4) * HWN + hw0 + tx * 4;
    float4 v[4];
#pragma unroll
    for (int q = 0; q < 4; ++q)
        v[q] = *(const float4*)(xb + (size_t)q * HWN);

    u16* dst = xT + ((size_t)b * HWN + hw0 + tx * 4) * CIN + c0 + ty * 4;
    const float* f = (const float*)v;
#pragma unroll
    for (int p = 0; p < 4; ++p) {
        uint2 o = {bf16_pack(f[0 * 4 + p], f[1 * 4 + p]),
                   bf16_pack(f[2 * 4 + p], f[3 * 4 + p])};
        *(uint2*)(dst + (size_t)p * CIN) = o;
    }
}

// ---------------------------------------------------------------------------
// MFMA GEMM, occupancy-first: BK=32, 2 LDS buffers (32 KB total),
// __launch_bounds__(256,4) -> 4 blocks/CU (16 waves) so TLP hides the
// per-step vmcnt drain (m114: wave-level overlap beats per-wave pipelining).
//   D[m=hw][n=o] = sum_k A[m][k] * Bw[n][k]   (per batch)
//   Per step: issue next-tile global_load_lds, compute current (8 ds_read +
//   16 MFMA), vmcnt(0)+barrier.
//   Bank swizzle slot ^= (row>>1)&3: <=2-way aliasing (free, m136).
//   XCD swizzle: 288-block chunk per XCD = one batch, by-minor so the 4
//   n-blocks sharing an A-panel are consecutive (A L2-resident; R8-verified).
// ---------------------------------------------------------------------------
template<int KDIM, int MODE>
__global__ __launch_bounds__(256, 4) void gemm_kernel(
    const u16* __restrict__ A,
    const u16* __restrict__ Bw,
    const float* __restrict__ b0, const float* __restrict__ b1,
    const float* __restrict__ resid,
    void* __restrict__ out0_, void* __restrict__ out1_)
{
    __shared__ u16 As[2][128 * 32];
    __shared__ u16 Bs[2][128 * 32];

    constexpr int NSTEP = KDIM / 32;
    constexpr int NWG = 72 * 4 * NB;

    // bijective XCD swizzle, by-minor within each XCD chunk
    const int id = blockIdx.x;
    const int swz = (id & 7) * (NWG / 8) + (id >> 3);
    const int u = swz % 288;
    const int bz = swz / 288;
    const int by = u & 3;
    const int bx = u >> 2;

    const int t = threadIdx.x;
    const int m0 = bx * 128;
    const int n0 = by * 128;
    const int w = t >> 6, l = t & 63;
    const int wr = w >> 1, wc = w & 1;
    const int g = l >> 4, li = l & 15;

    const u16* Ab = A + (size_t)bz * HWN * KDIM + (size_t)m0 * KDIM;
    const u16* Bb = Bw + (size_t)n0 * KDIM;

    f32x4 zero = {0.f, 0.f, 0.f, 0.f};
    f32x4 acc[4][4];
#pragma unroll
    for (int i = 0; i < 4; ++i)
#pragma unroll
        for (int j = 0; j < 4; ++j) acc[i][j] = zero;

    // stage one K=32 step into buffer buf.
    // chunk c in [0,512): row=c>>2, physical slot=c&3; global slot = phys ^
    // ((row>>1)&3); LDS linear at c*16B (lane-contiguous, m104-safe).
    auto stage = [&](int step, int buf) {
#pragma unroll
        for (int j = 0; j < 2; ++j) {
            int c = j * 256 + t;
            int row = c >> 2, slot = c & 3;
            int ss = slot ^ ((row >> 1) & 3);
            gload16(Ab + (size_t)row * KDIM + step * 32 + ss * 8, &As[buf][c * 8]);
        }
#pragma unroll
        for (int j = 0; j < 2; ++j) {
            int c = j * 256 + t;
            int row = c >> 2, slot = c & 3;
            int ss = slot ^ ((row >> 1) & 3);
            gload16(Bb + (size_t)row * KDIM + step * 32 + ss * 8, &Bs[buf][c * 8]);
        }
    };

    // prologue: stage step 0
    stage(0, 0);
    asm volatile("s_waitcnt vmcnt(0)" ::: "memory");
    __builtin_amdgcn_s_barrier();

    int cur = 0;
#pragma unroll 1
    for (int s = 0; s < NSTEP; ++s) {
        // issue next tile (overwrites buffer whose reads finished at the
        // barrier ending step s-1); latency hides under this step's compute
        if (s + 1 < NSTEP) stage(s + 1, cur ^ 1);

        bf16x8 af[4], bv[4];
#pragma unroll
        for (int mi = 0; mi < 4; ++mi) {
            int r = wr * 64 + mi * 16 + li;
            int sl = g ^ ((r >> 1) & 3);
            af[mi] = *(const bf16x8*)&As[cur][r * 32 + sl * 8];
        }
#pragma unroll
        for (int ni = 0; ni < 4; ++ni) {
            int r = wc * 64 + ni * 16 + li;
            int sl = g ^ ((r >> 1) & 3);
            bv[ni] = *(const bf16x8*)&Bs[cur][r * 32 + sl * 8];
        }
#pragma unroll
        for (int mi = 0; mi < 4; ++mi)
#pragma unroll
            for (int ni = 0; ni < 4; ++ni)
                acc[mi][ni] = __builtin_amdgcn_mfma_f32_16x16x32_bf16(
                    af[mi], bv[ni], acc[mi][ni], 0, 0, 0);

        if (s + 1 < NSTEP) {
            asm volatile("s_waitcnt vmcnt(0)" ::: "memory");
            __builtin_amdgcn_s_barrier();
            cur ^= 1;
        }
    }

    // ---- epilogue: transposed store D[m][n] -> dst[n][m] ----
#pragma unroll
    for (int ni = 0; ni < 4; ++ni) {
        int n = n0 + wc * 64 + ni * 16 + li;
        if constexpr (MODE == 0) {
            float bias = (n < 256) ? b0[n] : b1[n - 256];
            u16* dst = (u16*)((n < 256) ? out0_ : out1_) + ((size_t)bz * 256 + (n & 255)) * HWN;
#pragma unroll
            for (int mi = 0; mi < 4; ++mi) {
                int m = m0 + wr * 64 + mi * 16 + (g << 2);
                f32x4 v = acc[mi][ni];
                float e0 = fmaxf(v.x + bias, 0.f), e1 = fmaxf(v.y + bias, 0.f);
                float e2 = fmaxf(v.z + bias, 0.f), e3 = fmaxf(v.w + bias, 0.f);
                uint2 pk = {bf16_pack(e0, e1), bf16_pack(e2, e3)};
                *(uint2*)(dst + m) = pk;
            }
        } else {
            float bias = b0[n];
            float* dst = (float*)out0_ + ((size_t)bz * 512 + n) * HWN;
            const float* res = resid + ((size_t)bz * 512 + n) * HWN;
#pragma unroll
            for (int mi = 0; mi < 4; ++mi) {
                int m = m0 + wr * 64 + mi * 16 + (g << 2);
                f32x4 v = acc[mi][ni];
                float4 rx = *(const float4*)(res + m);
                float4 o = {v.x + bias + rx.x, v.y + bias + rx.y,
                            v.z + bias + rx.z, v.w + bias + rx.w};
                *(float4*)(dst + m) = o;
            }
        }
    }
}

// ---------------------------------------------------------------------------
// SPP pooling, fp32 input (x) -> xp [B][512][110] fp32
// ---------------------------------------------------------------------------
__global__ __launch_bounds__(256) void pool_x_kernel(
    const float* __restrict__ in, float* __restrict__ out)
{
    __shared__ float ps[576];
    const int plane = blockIdx.x;
    const float* p = in + (size_t)plane * HWN;
    const int t = threadIdx.x;

    for (int i = t; i < 576; i += 256) {
        int bh = i / 24, bw = i % 24;
        float s = 0.f;
#pragma unroll
        for (int r = 0; r < 4; ++r) {
            float4 v = *(const float4*)&p[(bh * 4 + r) * 96 + bw * 4];
            s += v.x + v.y + v.z + v.w;
        }
        ps[i] = s;
    }
    __syncthreads();

    if (t < KP) {
        float s = 0.f;
        if (t == 0) {
            for (int i = 0; i < 576; ++i) s += ps[i];
            s *= (1.0f / 9216.0f);
        } else if (t < 10) {
            int idx = t - 1, bi = idx / 3, bj = idx % 3;
            for (int r = 0; r < 8; ++r)
                for (int c = 0; c < 8; ++c)
                    s += ps[(bi * 8 + r) * 24 + bj * 8 + c];
            s *= (1.0f / 1024.0f);
        } else if (t < 46) {
            int idx = t - 10, bi = idx / 6, bj = idx % 6;
            for (int r = 0; r < 4; ++r)
                for (int c = 0; c < 4; ++c)
                    s += ps[(bi * 4 + r) * 24 + bj * 4 + c];
            s *= (1.0f / 256.0f);
        } else {
            int idx = t - 46, bi = idx / 8, bj = idx % 8;
            for (int r = 0; r < 3; ++r)
                for (int c = 0; c < 3; ++c)
                    s += ps[(bi * 3 + r) * 24 + bj * 3 + c];
            s *= (1.0f / 144.0f);
        }
        out[(size_t)plane * KP + t] = s;
    }
}

// ---------------------------------------------------------------------------
// SPP pooling, bf16 input (theta) -> tpT [B][128][256] bf16 transposed, padded
// ---------------------------------------------------------------------------
__global__ __launch_bounds__(256) void pool_t_kernel(
    const u16* __restrict__ in, u16* __restrict__ outT)
{
    __shared__ float ps[576];
    const int plane = blockIdx.x;
    const int b = plane >> 8, c = plane & 255;
    const u16* p = in + (size_t)plane * HWN;
    const int t = threadIdx.x;

    for (int i = t; i < 576; i += 256) {
        int bh = i / 24, bw = i % 24;
        float s = 0.f;
#pragma unroll
        for (int r = 0; r < 4; ++r) {
            ushort4 v = *(const ushort4*)&p[(bh * 4 + r) * 96 + bw * 4];
            s += b2f(v.x) + b2f(v.y) + b2f(v.z) + b2f(v.w);
        }
        ps[i] = s;
    }
    __syncthreads();

    if (t < 128) {
        float s = 0.f;
        if (t == 0) {
            for (int i = 0; i < 576; ++i) s += ps[i];
            s *= (1.0f / 9216.0f);
        } else if (t < 10) {
            int idx = t - 1, bi = idx / 3, bj = idx % 3;
            for (int r = 0; r < 8; ++r)
                for (int cc = 0; cc < 8; ++cc)
                    s += ps[(bi * 8 + r) * 24 + bj * 8 + cc];
            s *= (1.0f / 1024.0f);
        } else if (t < 46) {
            int idx = t - 10, bi = idx / 6, bj = idx % 6;
            for (int r = 0; r < 4; ++r)
                for (int cc = 0; cc < 4; ++cc)
                    s += ps[(bi * 4 + r) * 24 + bj * 4 + cc];
            s *= (1.0f / 256.0f);
        } else if (t < KP) {
            int idx = t - 46, bi = idx / 8, bj = idx % 8;
            for (int r = 0; r < 3; ++r)
                for (int cc = 0; cc < 3; ++cc)
                    s += ps[(bi * 3 + r) * 24 + bj * 3 + cc];
            s *= (1.0f / 144.0f);
        } else {
            s = 0.f;
        }
        outT[((size_t)b * 128 + t) * 256 + c] = (u16)bf16_1(s);
    }
}

// ---------------------------------------------------------------------------
// gamma_p k-minor: gp[b][c][k] bf16, k padded to 128 with zeros
// ---------------------------------------------------------------------------
__global__ __launch_bounds__(256) void gammap_kernel(
    const float* __restrict__ xp,
    const float* __restrict__ gw,
    const float* __restrict__ gb,
    u16* __restrict__ gp)
{
    const int k = blockIdx.x, b = blockIdx.y;
    const int t = threadIdx.x;
    if (k >= KP) {
        gp[((size_t)b * 256 + t) * 128 + k] = 0;
        return;
    }
    __shared__ float xc[512];
    xc[t]       = xp[((size_t)b * CIN + t) * KP + k];
    xc[t + 256] = xp[((size_t)b * CIN + t + 256) * KP + k];
    __syncthreads();

    float acc = gb[t];
    const float* wrow = gw + (size_t)t * CIN;
#pragma unroll 4
    for (int c = 0; c < CIN; c += 4) {
        float4 wv = *(const float4*)&wrow[c];
        acc = fmaf(wv.x, xc[c], acc);
        acc = fmaf(wv.y, xc[c + 1], acc);
        acc = fmaf(wv.z, xc[c + 2], acc);
        acc = fmaf(wv.w, xc[c + 3], acc);
    }
    gp[((size_t)b * 256 + t) * 128 + k] = (u16)bf16_1(acc);
}

// ---------------------------------------------------------------------------
// MFMA attention with m97-style LDS staging (unchanged).
// ---------------------------------------------------------------------------
__global__ __launch_bounds__(256) void attn_kernel(
    const u16* __restrict__ phi,   // [B][256][9216] bf16
    const u16* __restrict__ tpT,   // [B][128][256] bf16
    const u16* __restrict__ gp,    // [B][256][128] bf16
    u16* __restrict__ y2T)         // [B][9216 hw'][256 ci] bf16
{
    __shared__ __align__(16) u16 smem[32768];   // 64 KB
    u16* As = smem;
    u16* Bs = smem + 8192;
    char* Pb = (char*)(smem + 16384);

    const int t = threadIdx.x;
    const int w = t >> 6, l = t & 63;
    const int g = l >> 4, li = l & 15;
    const int b = blockIdx.y;
    const int rr = blockIdx.x >> 1;
    const int ci0 = (blockIdx.x & 1) << 7;

    const u16* phib = phi + (size_t)b * (OIN * HWN);
    const u16* tpb  = tpT + (size_t)b * (128 * 256);
    const u16* gpb  = gp  + (size_t)b * (256 * 128);

    const int srow = t >> 3;
    const int su = t & 7;

    f32x4 zero = {0.f, 0.f, 0.f, 0.f};
    f32x4 acc[2][8];
#pragma unroll
    for (int i = 0; i < 2; ++i)
#pragma unroll
        for (int j = 0; j < 8; ++j) acc[i][j] = zero;

    for (int kt = 0; kt < 256; kt += 64) {
#pragma unroll
        for (int cc = 0; cc < 4; ++cc) {
            int row = cc * 32 + srow;
            int ss = su ^ (row & 7);
            gload16(phib + (size_t)(ci0 + row) * HWN + rr * 256 + kt + ss * 8,
                    &As[(row * 8 + su) * 8]);
        }
#pragma unroll
        for (int cc = 0; cc < 4; ++cc) {
            int row = cc * 32 + srow;
            int ss = su ^ (row & 7);
            gload16(tpb + (size_t)row * 256 + kt + ss * 8,
                    &Bs[(row * 8 + su) * 8]);
        }
        __syncthreads();

#pragma unroll
        for (int h = 0; h < 2; ++h) {
            bf16x8 af[2], bfr[8];
#pragma unroll
            for (int mi = 0; mi < 2; ++mi) {
                int r = w * 32 + mi * 16 + li;
                af[mi] = *(const bf16x8*)&As[r * 64 + (((h * 4 + g) ^ (r & 7)) << 3)];
            }
#pragma unroll
            for (int ni = 0; ni < 8; ++ni) {
                int r = ni * 16 + li;
                bfr[ni] = *(const bf16x8*)&Bs[r * 64 + (((h * 4 + g) ^ (r & 7)) << 3)];
            }
#pragma unroll
            for (int mi = 0; mi < 2; ++mi)
#pragma unroll
                for (int ni = 0; ni < 8; ++ni)
                    acc[mi][ni] = __builtin_amdgcn_mfma_f32_16x16x32_bf16(
                        af[mi], bfr[ni], acc[mi][ni], 0, 0, 0);
        }
        __syncthreads();
    }

    bool vm[8];
#pragma unroll
    for (int ni = 0; ni < 8; ++ni) vm[ni] = (ni * 16 + li) < KP;

#pragma unroll
    for (int mi = 0; mi < 2; ++mi) {
#pragma unroll
        for (int r = 0; r < 4; ++r) {
            float mx = -1e30f;
#pragma unroll
            for (int ni = 0; ni < 8; ++ni)
                if (vm[ni]) mx = fmaxf(mx, acc[mi][ni][r] * SCL);
            mx = fmaxf(mx, __shfl_xor(mx, 1));
            mx = fmaxf(mx, __shfl_xor(mx, 2));
            mx = fmaxf(mx, __shfl_xor(mx, 4));
            mx = fmaxf(mx, __shfl_xor(mx, 8));
            float s = 0.f;
#pragma unroll
            for (int ni = 0; ni < 8; ++ni) {
                float e = vm[ni] ? __expf(acc[mi][ni][r] * SCL - mx) : 0.f;
                acc[mi][ni][r] = e;
                s += e;
            }
            s += __shfl_xor(s, 1);
            s += __shfl_xor(s, 2);
            s += __shfl_xor(s, 4);
            s += __shfl_xor(s, 8);
            float inv = 1.0f / s;
#pragma unroll
            for (int ni = 0; ni < 8; ++ni) acc[mi][ni][r] *= inv;
        }
#pragma unroll
        for (int ni = 0; ni < 8; ++ni)
#pragma unroll
            for (int r = 0; r < 4; ++r) {
                int row = w * 32 + mi * 16 + g * 4 + r;
                int col = ni * 16 + li;
                *(short*)(Pb + row * 256 + (((col >> 3) ^ (row & 7)) << 4) + ((col & 7) << 1)) =
                    (short)bf16_1(acc[mi][ni][r]);
            }
    }

    f32x4 acc2[2][16];
#pragma unroll
    for (int i = 0; i < 2; ++i)
#pragma unroll
        for (int j = 0; j < 16; ++j) acc2[i][j] = zero;

#pragma unroll 1
    for (int ks2 = 0; ks2 < 2; ++ks2) {
#pragma unroll
        for (int cc = 0; cc < 8; ++cc) {
            int row = cc * 32 + srow;
            int ss = su ^ (row & 7);
            gload16(gpb + (size_t)row * 128 + ks2 * 64 + ss * 8,
                    &smem[(row * 8 + su) * 8]);
        }
        __syncthreads();

#pragma unroll
        for (int h = 0; h < 2; ++h) {
            bf16x8 a2[2];
#pragma unroll
            for (int mi = 0; mi < 2; ++mi) {
                int prow = w * 32 + mi * 16 + li;
                int s = ks2 * 8 + h * 4 + g;
                a2[mi] = *(const bf16x8*)(Pb + prow * 256 + ((s ^ (prow & 7)) << 4));
            }
#pragma unroll
            for (int cf = 0; cf < 16; ++cf) {
                int crow = cf * 16 + li;
                bf16x8 bv = *(const bf16x8*)&smem[crow * 64 + (((h * 4 + g) ^ (crow & 7)) << 3)];
#pragma unroll
                for (int mi = 0; mi < 2; ++mi)
                    acc2[mi][cf] = __builtin_amdgcn_mfma_f32_16x16x32_bf16(
                        a2[mi], bv, acc2[mi][cf], 0, 0, 0);
            }
        }
        __syncthreads();
    }

#pragma unroll
    for (int mi = 0; mi < 2; ++mi)
#pragma unroll
        for (int cf = 0; cf < 16; ++cf) {
            int c = cf * 16 + li;
            int cib = w * 32 + mi * 16 + g * 4;
            int e0 = c * 128 + (cib ^ (li << 3));
            unsigned d0 = bf16_pack(acc2[mi][cf][0], acc2[mi][cf][1]);
            unsigned d1 = bf16_pack(acc2[mi][cf][2], acc2[mi][cf][3]);
            *(unsigned*)((char*)smem + (size_t)e0 * 2) = d0;
            *(unsigned*)((char*)smem + (size_t)e0 * 2 + 4) = d1;
        }

    __syncthreads();

    {
        u16* yb = y2T + ((size_t)b * HWN + rr * 256) * 256 + ci0;
#pragma unroll
        for (int j = 0; j < 16; ++j) {
            int c = (t >> 4) + (j << 4);
            int e = c * 128 + (((t & 15) ^ (t >> 4)) << 3);
            uint4 v = *(const uint4*)((char*)smem + (size_t)e * 2);
            *(uint4*)(yb + (size_t)c * 256 + (t & 15) * 8) = v;
        }
    }
}

extern "C" void kernel_launch(void* const* d_in, const int* in_sizes, int n_in,
                              void* d_out, int out_size, void* d_ws, size_t ws_size,
                              hipStream_t stream)
{
    const float* x       = (const float*)d_in[0];
    const float* phi_w   = (const float*)d_in[1];
    const float* phi_b   = (const float*)d_in[2];
    const float* theta_w = (const float*)d_in[3];
    const float* theta_b = (const float*)d_in[4];
    const float* gamma_w = (const float*)d_in[5];
    const float* gamma_b = (const float*)d_in[6];
    const float* W_w     = (const float*)d_in[7];
    const float* W_b     = (const float*)d_in[8];
    float* out = (float*)d_out;

    char* p = (char*)d_ws;
    u16* xT     = (u16*)p;  p += (size_t)NB * HWN * CIN * 2;   // 75.5 MB
    u16* phi_bf = (u16*)p;  p += (size_t)NB * OIN * HWN * 2;   // 37.7 MB
    u16* th_y2  = (u16*)p;  p += (size_t)NB * OIN * HWN * 2;   // 37.7 MB (theta, then y2T)
    float* xp   = (float*)p; p += (size_t)NB * CIN * KP * 4;
    u16* tpT    = (u16*)p;  p += (size_t)NB * 128 * 256 * 2;
    u16* gp     = (u16*)p;  p += (size_t)NB * 256 * 128 * 2;
    u16* Wcat   = (u16*)p;  p += 512 * 512 * 2;
    u16* Wwb    = (u16*)p;  p += 512 * 256 * 2;

    castw_kernel<<<1536, 256, 0, stream>>>(phi_w, theta_w, W_w, Wcat, Wwb);
    castx_kernel<<<dim3(144, 8, NB), 256, 0, stream>>>(x, xT);
    gemm_kernel<512, 0><<<dim3(72 * 4 * NB), 256, 0, stream>>>(
        xT, Wcat, phi_b, theta_b, nullptr, phi_bf, th_y2);
    pool_x_kernel<<<dim3(NB * CIN), 256, 0, stream>>>(x, xp);
    pool_t_kernel<<<dim3(NB * OIN), 256, 0, stream>>>(th_y2, tpT);
    gammap_kernel<<<dim3(128, NB), 256, 0, stream>>>(xp, gamma_w, gamma_b, gp);
    attn_kernel<<<dim3(72, NB), 256, 0, stream>>>(phi_bf, tpT, gp, th_y2);
    gemm_kernel<256, 1><<<dim3(72 * 4 * NB), 256, 0, stream>>>(
        th_y2, Wwb, W_b, nullptr, x, out, nullptr);
}

// Round 10
// 307.481 us; speedup vs baseline: 1.1985x; 1.1350x over previous
//
#include <hip/hip_runtime.h>

#define NB 8
#define CIN 512
#define OIN 256
#define HWN 9216
#define KP 110
#define SCL 0.10206207261596577f  // 9216^(-0.25)

typedef __attribute__((ext_vector_type(8))) short bf16x8;
typedef __attribute__((ext_vector_type(4))) float f32x4;
typedef unsigned short u16;

__device__ inline unsigned bf16_1(float a) {
    unsigned u = __builtin_bit_cast(unsigned, a);
    return (u + 0x7fffu + ((u >> 16) & 1u)) >> 16;
}
__device__ inline unsigned bf16_pack(float a, float b) {
    return bf16_1(a) | (bf16_1(b) << 16);
}
__device__ inline float b2f(u16 u) {
    return __builtin_bit_cast(float, ((unsigned)u) << 16);
}

__device__ __forceinline__ void gload16(const u16* g, u16* l) {
    __builtin_amdgcn_global_load_lds(
        (const __attribute__((address_space(1))) unsigned int*)g,
        (__attribute__((address_space(3))) unsigned int*)l, 16, 0, 0);
}

// ---------------------------------------------------------------------------
// Weight cast: phi_w+theta_w -> Wcat bf16 [512][512]; W_w -> Wwb bf16 [512][256]
// ---------------------------------------------------------------------------
__global__ __launch_bounds__(256) void castw_kernel(
    const float* __restrict__ phi_w, const float* __restrict__ theta_w,
    const float* __restrict__ Ww,
    u16* __restrict__ Wcat, u16* __restrict__ Wwb)
{
    int i = blockIdx.x * 256 + threadIdx.x;
    if (i < 262144) {
        float v = (i < 131072) ? phi_w[i] : theta_w[i - 131072];
        Wcat[i] = (u16)bf16_1(v);
    } else {
        int j = i - 262144;
        Wwb[j] = (u16)bf16_1(Ww[j]);
    }
}

// ---------------------------------------------------------------------------
// castx: x fp32 [b][512 c][9216 hw] -> xT bf16 [b][9216 hw][512 c]
// ---------------------------------------------------------------------------
__global__ __launch_bounds__(256) void castx_kernel(
    const float* __restrict__ x, u16* __restrict__ xT)
{
    const int t = threadIdx.x;
    const int tx = t & 15, ty = t >> 4;
    const int b = blockIdx.z;
    const int c0 = blockIdx.y * 64;
    const int hw0 = blockIdx.x * 64;

    const float* xb = x + ((size_t)b * CIN + c0 + ty * 4) * HWN + hw0 + tx * 4;
    float4 v[4];
#pragma unroll
    for (int q = 0; q < 4; ++q)
        v[q] = *(const float4*)(xb + (size_t)q * HWN);

    u16* dst = xT + ((size_t)b * HWN + hw0 + tx * 4) * CIN + c0 + ty * 4;
    const float* f = (const float*)v;
#pragma unroll
    for (int p = 0; p < 4; ++p) {
        uint2 o = {bf16_pack(f[0 * 4 + p], f[1 * 4 + p]),
                   bf16_pack(f[2 * 4 + p], f[3 * 4 + p])};
        *(uint2*)(dst + (size_t)p * CIN) = o;
    }
}

// ---------------------------------------------------------------------------
// MFMA GEMM (unchanged from R9): BK=32, 2 LDS buffers (32 KB), 4 blocks/CU.
// ---------------------------------------------------------------------------
template<int KDIM, int MODE>
__global__ __launch_bounds__(256, 4) void gemm_kernel(
    const u16* __restrict__ A,
    const u16* __restrict__ Bw,
    const float* __restrict__ b0, const float* __restrict__ b1,
    const float* __restrict__ resid,
    void* __restrict__ out0_, void* __restrict__ out1_)
{
    __shared__ u16 As[2][128 * 32];
    __shared__ u16 Bs[2][128 * 32];

    constexpr int NSTEP = KDIM / 32;
    constexpr int NWG = 72 * 4 * NB;

    const int id = blockIdx.x;
    const int swz = (id & 7) * (NWG / 8) + (id >> 3);
    const int u = swz % 288;
    const int bz = swz / 288;
    const int by = u & 3;
    const int bx = u >> 2;

    const int t = threadIdx.x;
    const int m0 = bx * 128;
    const int n0 = by * 128;
    const int w = t >> 6, l = t & 63;
    const int wr = w >> 1, wc = w & 1;
    const int g = l >> 4, li = l & 15;

    const u16* Ab = A + (size_t)bz * HWN * KDIM + (size_t)m0 * KDIM;
    const u16* Bb = Bw + (size_t)n0 * KDIM;

    f32x4 zero = {0.f, 0.f, 0.f, 0.f};
    f32x4 acc[4][4];
#pragma unroll
    for (int i = 0; i < 4; ++i)
#pragma unroll
        for (int j = 0; j < 4; ++j) acc[i][j] = zero;

    auto stage = [&](int step, int buf) {
#pragma unroll
        for (int j = 0; j < 2; ++j) {
            int c = j * 256 + t;
            int row = c >> 2, slot = c & 3;
            int ss = slot ^ ((row >> 1) & 3);
            gload16(Ab + (size_t)row * KDIM + step * 32 + ss * 8, &As[buf][c * 8]);
        }
#pragma unroll
        for (int j = 0; j < 2; ++j) {
            int c = j * 256 + t;
            int row = c >> 2, slot = c & 3;
            int ss = slot ^ ((row >> 1) & 3);
            gload16(Bb + (size_t)row * KDIM + step * 32 + ss * 8, &Bs[buf][c * 8]);
        }
    };

    stage(0, 0);
    asm volatile("s_waitcnt vmcnt(0)" ::: "memory");
    __builtin_amdgcn_s_barrier();

    int cur = 0;
#pragma unroll 1
    for (int s = 0; s < NSTEP; ++s) {
        if (s + 1 < NSTEP) stage(s + 1, cur ^ 1);

        bf16x8 af[4], bv[4];
#pragma unroll
        for (int mi = 0; mi < 4; ++mi) {
            int r = wr * 64 + mi * 16 + li;
            int sl = g ^ ((r >> 1) & 3);
            af[mi] = *(const bf16x8*)&As[cur][r * 32 + sl * 8];
        }
#pragma unroll
        for (int ni = 0; ni < 4; ++ni) {
            int r = wc * 64 + ni * 16 + li;
            int sl = g ^ ((r >> 1) & 3);
            bv[ni] = *(const bf16x8*)&Bs[cur][r * 32 + sl * 8];
        }
#pragma unroll
        for (int mi = 0; mi < 4; ++mi)
#pragma unroll
            for (int ni = 0; ni < 4; ++ni)
                acc[mi][ni] = __builtin_amdgcn_mfma_f32_16x16x32_bf16(
                    af[mi], bv[ni], acc[mi][ni], 0, 0, 0);

        if (s + 1 < NSTEP) {
            asm volatile("s_waitcnt vmcnt(0)" ::: "memory");
            __builtin_amdgcn_s_barrier();
            cur ^= 1;
        }
    }

#pragma unroll
    for (int ni = 0; ni < 4; ++ni) {
        int n = n0 + wc * 64 + ni * 16 + li;
        if constexpr (MODE == 0) {
            float bias = (n < 256) ? b0[n] : b1[n - 256];
            u16* dst = (u16*)((n < 256) ? out0_ : out1_) + ((size_t)bz * 256 + (n & 255)) * HWN;
#pragma unroll
            for (int mi = 0; mi < 4; ++mi) {
                int m = m0 + wr * 64 + mi * 16 + (g << 2);
                f32x4 v = acc[mi][ni];
                float e0 = fmaxf(v.x + bias, 0.f), e1 = fmaxf(v.y + bias, 0.f);
                float e2 = fmaxf(v.z + bias, 0.f), e3 = fmaxf(v.w + bias, 0.f);
                uint2 pk = {bf16_pack(e0, e1), bf16_pack(e2, e3)};
                *(uint2*)(dst + m) = pk;
            }
        } else {
            float bias = b0[n];
            float* dst = (float*)out0_ + ((size_t)bz * 512 + n) * HWN;
            const float* res = resid + ((size_t)bz * 512 + n) * HWN;
#pragma unroll
            for (int mi = 0; mi < 4; ++mi) {
                int m = m0 + wr * 64 + mi * 16 + (g << 2);
                f32x4 v = acc[mi][ni];
                float4 rx = *(const float4*)(res + m);
                float4 o = {v.x + bias + rx.x, v.y + bias + rx.y,
                            v.z + bias + rx.z, v.w + bias + rx.w};
                *(float4*)(dst + m) = o;
            }
        }
    }
}

// ---------------------------------------------------------------------------
// SPP pooling, fp32 input (x) -> xp [B][512][110] fp32
// ---------------------------------------------------------------------------
__global__ __launch_bounds__(256) void pool_x_kernel(
    const float* __restrict__ in, float* __restrict__ out)
{
    __shared__ float ps[576];
    const int plane = blockIdx.x;
    const float* p = in + (size_t)plane * HWN;
    const int t = threadIdx.x;

    for (int i = t; i < 576; i += 256) {
        int bh = i / 24, bw = i % 24;
        float s = 0.f;
#pragma unroll
        for (int r = 0; r < 4; ++r) {
            float4 v = *(const float4*)&p[(bh * 4 + r) * 96 + bw * 4];
            s += v.x + v.y + v.z + v.w;
        }
        ps[i] = s;
    }
    __syncthreads();

    if (t < KP) {
        float s = 0.f;
        if (t == 0) {
            for (int i = 0; i < 576; ++i) s += ps[i];
            s *= (1.0f / 9216.0f);
        } else if (t < 10) {
            int idx = t - 1, bi = idx / 3, bj = idx % 3;
            for (int r = 0; r < 8; ++r)
                for (int c = 0; c < 8; ++c)
                    s += ps[(bi * 8 + r) * 24 + bj * 8 + c];
            s *= (1.0f / 1024.0f);
        } else if (t < 46) {
            int idx = t - 10, bi = idx / 6, bj = idx % 6;
            for (int r = 0; r < 4; ++r)
                for (int c = 0; c < 4; ++c)
                    s += ps[(bi * 4 + r) * 24 + bj * 4 + c];
            s *= (1.0f / 256.0f);
        } else {
            int idx = t - 46, bi = idx / 8, bj = idx % 8;
            for (int r = 0; r < 3; ++r)
                for (int c = 0; c < 3; ++c)
                    s += ps[(bi * 3 + r) * 24 + bj * 3 + c];
            s *= (1.0f / 144.0f);
        }
        out[(size_t)plane * KP + t] = s;
    }
}

// ---------------------------------------------------------------------------
// SPP pooling, bf16 input (theta) -> tpT [B][128][256] bf16 transposed, padded
// ---------------------------------------------------------------------------
__global__ __launch_bounds__(256) void pool_t_kernel(
    const u16* __restrict__ in, u16* __restrict__ outT)
{
    __shared__ float ps[576];
    const int plane = blockIdx.x;
    const int b = plane >> 8, c = plane & 255;
    const u16* p = in + (size_t)plane * HWN;
    const int t = threadIdx.x;

    for (int i = t; i < 576; i += 256) {
        int bh = i / 24, bw = i % 24;
        float s = 0.f;
#pragma unroll
        for (int r = 0; r < 4; ++r) {
            ushort4 v = *(const ushort4*)&p[(bh * 4 + r) * 96 + bw * 4];
            s += b2f(v.x) + b2f(v.y) + b2f(v.z) + b2f(v.w);
        }
        ps[i] = s;
    }
    __syncthreads();

    if (t < 128) {
        float s = 0.f;
        if (t == 0) {
            for (int i = 0; i < 576; ++i) s += ps[i];
            s *= (1.0f / 9216.0f);
        } else if (t < 10) {
            int idx = t - 1, bi = idx / 3, bj = idx % 3;
            for (int r = 0; r < 8; ++r)
                for (int cc = 0; cc < 8; ++cc)
                    s += ps[(bi * 8 + r) * 24 + bj * 8 + cc];
            s *= (1.0f / 1024.0f);
        } else if (t < 46) {
            int idx = t - 10, bi = idx / 6, bj = idx % 6;
            for (int r = 0; r < 4; ++r)
                for (int cc = 0; cc < 4; ++cc)
                    s += ps[(bi * 4 + r) * 24 + bj * 4 + cc];
            s *= (1.0f / 256.0f);
        } else if (t < KP) {
            int idx = t - 46, bi = idx / 8, bj = idx % 8;
            for (int r = 0; r < 3; ++r)
                for (int cc = 0; cc < 3; ++cc)
                    s += ps[(bi * 3 + r) * 24 + bj * 3 + cc];
            s *= (1.0f / 144.0f);
        } else {
            s = 0.f;
        }
        outT[((size_t)b * 128 + t) * 256 + c] = (u16)bf16_1(s);
    }
}

// ---------------------------------------------------------------------------
// gamma_p k-minor, L2-efficient: block = 8 k values x 256 o.
// xc[8][512] staged in LDS; each thread's gw row read ONCE for 8 accumulators
// (previous version re-read all 512 KB of gw per k -> 512 MB L2 traffic).
// gp[b][c][k] bf16, k padded to 128 (pad values multiply P==0, don't matter).
// ---------------------------------------------------------------------------
__global__ __launch_bounds__(256) void gammap_kernel(
    const float* __restrict__ xp,   // [B][512][110]
    const float* __restrict__ gw,   // [256][512]
    const float* __restrict__ gb,   // [256]
    u16* __restrict__ gp)           // [B][256][128]
{
    __shared__ float xc[8][512];
    const int kb = blockIdx.x * 8, b = blockIdx.y;
    const int t = threadIdx.x;

#pragma unroll
    for (int j = 0; j < 16; ++j) {
        int idx = j * 256 + t;           // 0..4095
        int kk = idx >> 9, c = idx & 511;
        int k = kb + kk;
        xc[kk][c] = (k < KP) ? xp[((size_t)b * CIN + c) * KP + k] : 0.f;
    }
    __syncthreads();

    float bias = gb[t];
    float acc[8];
#pragma unroll
    for (int kk = 0; kk < 8; ++kk) acc[kk] = bias;

    const float* wrow = gw + (size_t)t * CIN;
#pragma unroll 2
    for (int c = 0; c < CIN; c += 4) {
        float4 wv = *(const float4*)&wrow[c];
#pragma unroll
        for (int kk = 0; kk < 8; ++kk) {
            acc[kk] = fmaf(wv.x, xc[kk][c], acc[kk]);
            acc[kk] = fmaf(wv.y, xc[kk][c + 1], acc[kk]);
            acc[kk] = fmaf(wv.z, xc[kk][c + 2], acc[kk]);
            acc[kk] = fmaf(wv.w, xc[kk][c + 3], acc[kk]);
        }
    }

    ushort4 o0, o1;
    o0.x = (u16)bf16_1(acc[0]); o0.y = (u16)bf16_1(acc[1]);
    o0.z = (u16)bf16_1(acc[2]); o0.w = (u16)bf16_1(acc[3]);
    o1.x = (u16)bf16_1(acc[4]); o1.y = (u16)bf16_1(acc[5]);
    o1.z = (u16)bf16_1(acc[6]); o1.w = (u16)bf16_1(acc[7]);
    u16* dst = gp + ((size_t)b * 256 + t) * 128 + kb;
    *(ushort4*)(dst) = o0;
    *(ushort4*)(dst + 4) = o1;
}

// ---------------------------------------------------------------------------
// MFMA attention, 64-ci blocks (2x grid of R9) for occupancy.
// Block = (rr, ci-quarter): rows n = rr + 36*ci, ci in [ci0, ci0+64).
// LDS (40 KB):
//   GEMM1: As [64][64] @0 (8K) + Bs [128][64] @8K (16K); P [64][128] @24K (16K)
//   GEMM2: Gs [256][32] chunks @0 (16K, 4 chunks)
//   y2 transpose tile [256 c][64 ci] @0 (32K; P dead by then)
// ---------------------------------------------------------------------------
__global__ __launch_bounds__(256, 4) void attn_kernel(
    const u16* __restrict__ phi,   // [B][256][9216] bf16
    const u16* __restrict__ tpT,   // [B][128][256] bf16
    const u16* __restrict__ gp,    // [B][256][128] bf16
    u16* __restrict__ y2T)         // [B][9216 hw'][256 ci] bf16
{
    __shared__ __align__(16) char smem[40960];
    u16* As = (u16*)smem;              // 4096 u16
    u16* Bs = (u16*)(smem + 8192);     // 8192 u16
    char* Pb = smem + 24576;           // 16 KB
    u16* Gs = (u16*)smem;              // GEMM2 chunks, 16 KB

    const int t = threadIdx.x;
    const int w = t >> 6, l = t & 63;
    const int g = l >> 4, li = l & 15;
    const int b = blockIdx.y;
    const int rr = blockIdx.x >> 2;          // 0..35
    const int ci0 = (blockIdx.x & 3) << 6;   // 0,64,128,192

    const u16* phib = phi + (size_t)b * (OIN * HWN);
    const u16* tpb  = tpT + (size_t)b * (128 * 256);
    const u16* gpb  = gp  + (size_t)b * (256 * 128);

    const int srow = t >> 3;   // 0..31
    const int su = t & 7;

    f32x4 zero = {0.f, 0.f, 0.f, 0.f};
    f32x4 acc[8];
#pragma unroll
    for (int j = 0; j < 8; ++j) acc[j] = zero;

    // ---------------- GEMM1: logits[64 ci][128 tok], K=256, BK=64 ----------
    for (int kt = 0; kt < 256; kt += 64) {
#pragma unroll
        for (int cc = 0; cc < 2; ++cc) {
            int row = cc * 32 + srow;                  // ci-local 0..63
            int ss = su ^ (row & 7);
            gload16(phib + (size_t)(ci0 + row) * HWN + rr * 256 + kt + ss * 8,
                    &As[(row * 8 + su) * 8]);
        }
#pragma unroll
        for (int cc = 0; cc < 4; ++cc) {
            int row = cc * 32 + srow;                  // tok 0..127
            int ss = su ^ (row & 7);
            gload16(tpb + (size_t)row * 256 + kt + ss * 8,
                    &Bs[(row * 8 + su) * 8]);
        }
        __syncthreads();

#pragma unroll
        for (int h = 0; h < 2; ++h) {
            int r = w * 16 + li;
            bf16x8 af = *(const bf16x8*)&As[r * 64 + (((h * 4 + g) ^ (r & 7)) << 3)];
            bf16x8 bfr[8];
#pragma unroll
            for (int ni = 0; ni < 8; ++ni) {
                int rb = ni * 16 + li;
                bfr[ni] = *(const bf16x8*)&Bs[rb * 64 + (((h * 4 + g) ^ (rb & 7)) << 3)];
            }
#pragma unroll
            for (int ni = 0; ni < 8; ++ni)
                acc[ni] = __builtin_amdgcn_mfma_f32_16x16x32_bf16(
                    af, bfr[ni], acc[ni], 0, 0, 0);
        }
        __syncthreads();
    }

    // ---------------- softmax over tokens (110 valid) ----------------
    bool vm[8];
#pragma unroll
    for (int ni = 0; ni < 8; ++ni) vm[ni] = (ni * 16 + li) < KP;

#pragma unroll
    for (int r = 0; r < 4; ++r) {
        float mx = -1e30f;
#pragma unroll
        for (int ni = 0; ni < 8; ++ni)
            if (vm[ni]) mx = fmaxf(mx, acc[ni][r] * SCL);
        mx = fmaxf(mx, __shfl_xor(mx, 1));
        mx = fmaxf(mx, __shfl_xor(mx, 2));
        mx = fmaxf(mx, __shfl_xor(mx, 4));
        mx = fmaxf(mx, __shfl_xor(mx, 8));
        float s = 0.f;
#pragma unroll
        for (int ni = 0; ni < 8; ++ni) {
            float e = vm[ni] ? __expf(acc[ni][r] * SCL - mx) : 0.f;
            acc[ni][r] = e;
            s += e;
        }
        s += __shfl_xor(s, 1);
        s += __shfl_xor(s, 2);
        s += __shfl_xor(s, 4);
        s += __shfl_xor(s, 8);
        float inv = 1.0f / s;
#pragma unroll
        for (int ni = 0; ni < 8; ++ni) acc[ni][r] *= inv;
    }
    // P rows -> Pb (wave-private rows; region untouched by GEMM1 staging)
#pragma unroll
    for (int ni = 0; ni < 8; ++ni)
#pragma unroll
        for (int r = 0; r < 4; ++r) {
            int row = w * 16 + g * 4 + r;      // 0..63
            int col = ni * 16 + li;            // 0..127
            *(short*)(Pb + row * 256 + (((col >> 3) ^ (row & 7)) << 4) + ((col & 7) << 1)) =
                (short)bf16_1(acc[ni][r]);
        }

    // ---------------- GEMM2: y2[64 ci][256 c], K=128 tok, 4 chunks of 32 ----
    f32x4 acc2[16];
#pragma unroll
    for (int j = 0; j < 16; ++j) acc2[j] = zero;

#pragma unroll 1
    for (int ch = 0; ch < 4; ++ch) {
        // stage Gs [256 c][32 tok] (16 KB): 4 gload16/thread, lane-linear dest
#pragma unroll
        for (int j = 0; j < 4; ++j) {
            int row = j * 64 + (t >> 2);       // c 0..255
            int slot = t & 3;
            int ss = slot ^ (row & 3);
            gload16(gpb + (size_t)row * 128 + ch * 32 + ss * 8,
                    &Gs[(j * 256 + t) * 8]);
        }
        __syncthreads();

        int prow = w * 16 + li;
        bf16x8 a2 = *(const bf16x8*)(Pb + prow * 256 + (((ch * 4 + g) ^ (prow & 7)) << 4));
#pragma unroll
        for (int cf = 0; cf < 16; ++cf) {
            int crow = cf * 16 + li;
            bf16x8 bv = *(const bf16x8*)((const char*)Gs + crow * 64 + ((g ^ (crow & 3)) << 4));
            acc2[cf] = __builtin_amdgcn_mfma_f32_16x16x32_bf16(a2, bv, acc2[cf], 0, 0, 0);
        }
        __syncthreads();
    }

    // ---------------- y2 -> LDS as [256 c][64 ci^swz] (32 KB @0) ------------
#pragma unroll
    for (int cf = 0; cf < 16; ++cf) {
        int c = cf * 16 + li;
        int cib = w * 16 + g * 4;              // 0..60
        int e0 = c * 64 + (cib ^ ((li & 7) << 3));
        unsigned d0 = bf16_pack(acc2[cf][0], acc2[cf][1]);
        unsigned d1 = bf16_pack(acc2[cf][2], acc2[cf][3]);
        *(unsigned*)(smem + (size_t)e0 * 2) = d0;
        *(unsigned*)(smem + (size_t)e0 * 2 + 4) = d1;
    }

    __syncthreads();

    // ---------------- coalesced y2T store (row c = t) ----------------
    {
        int c = t;                              // 0..255
        u16* dst = y2T + ((size_t)b * HWN + rr * 256 + c) * 256 + ci0;
#pragma unroll
        for (int j = 0; j < 8; ++j) {
            // stored column group for original group j is j ^ (c&7)
            uint4 v = *(const uint4*)(smem + c * 128 + ((j ^ (c & 7)) << 4));
            *(uint4*)(dst + j * 8) = v;
        }
    }
}

extern "C" void kernel_launch(void* const* d_in, const int* in_sizes, int n_in,
                              void* d_out, int out_size, void* d_ws, size_t ws_size,
                              hipStream_t stream)
{
    const float* x       = (const float*)d_in[0];
    const float* phi_w   = (const float*)d_in[1];
    const float* phi_b   = (const float*)d_in[2];
    const float* theta_w = (const float*)d_in[3];
    const float* theta_b = (const float*)d_in[4];
    const float* gamma_w = (const float*)d_in[5];
    const float* gamma_b = (const float*)d_in[6];
    const float* W_w     = (const float*)d_in[7];
    const float* W_b     = (const float*)d_in[8];
    float* out = (float*)d_out;

    char* p = (char*)d_ws;
    u16* xT     = (u16*)p;  p += (size_t)NB * HWN * CIN * 2;   // 75.5 MB
    u16* phi_bf = (u16*)p;  p += (size_t)NB * OIN * HWN * 2;   // 37.7 MB
    u16* th_y2  = (u16*)p;  p += (size_t)NB * OIN * HWN * 2;   // 37.7 MB (theta, then y2T)
    float* xp   = (float*)p; p += (size_t)NB * CIN * KP * 4;
    u16* tpT    = (u16*)p;  p += (size_t)NB * 128 * 256 * 2;
    u16* gp     = (u16*)p;  p += (size_t)NB * 256 * 128 * 2;
    u16* Wcat   = (u16*)p;  p += 512 * 512 * 2;
    u16* Wwb    = (u16*)p;  p += 512 * 256 * 2;

    castw_kernel<<<1536, 256, 0, stream>>>(phi_w, theta_w, W_w, Wcat, Wwb);
    castx_kernel<<<dim3(144, 8, NB), 256, 0, stream>>>(x, xT);
    // pool_x right after castx: x still L3-resident from castx's read
    pool_x_kernel<<<dim3(NB * CIN), 256, 0, stream>>>(x, xp);
    gemm_kernel<512, 0><<<dim3(72 * 4 * NB), 256, 0, stream>>>(
        xT, Wcat, phi_b, theta_b, nullptr, phi_bf, th_y2);
    pool_t_kernel<<<dim3(NB * OIN), 256, 0, stream>>>(th_y2, tpT);
    gammap_kernel<<<dim3(16, NB), 256, 0, stream>>>(xp, gamma_w, gamma_b, gp);
    attn_kernel<<<dim3(144, NB), 256, 0, stream>>>(phi_bf, tpT, gp, th_y2);
    gemm_kernel<256, 1><<<dim3(72 * 4 * NB), 256, 0, stream>>>(
        th_y2, Wwb, W_b, nullptr, x, out, nullptr);
}

// Round 11
// 306.417 us; speedup vs baseline: 1.2026x; 1.0035x over previous
//
#include <hip/hip_runtime.h>

#define NB 8
#define CIN 512
#define OIN 256
#define HWN 9216
#define KP 110
#define SCL 0.10206207261596577f  // 9216^(-0.25)

typedef __attribute__((ext_vector_type(8))) short bf16x8;
typedef __attribute__((ext_vector_type(4))) float f32x4;
typedef unsigned short u16;

__device__ inline unsigned bf16_1(float a) {
    unsigned u = __builtin_bit_cast(unsigned, a);
    return (u + 0x7fffu + ((u >> 16) & 1u)) >> 16;
}
__device__ inline unsigned bf16_pack(float a, float b) {
    return bf16_1(a) | (bf16_1(b) << 16);
}
__device__ inline float b2f(u16 u) {
    return __builtin_bit_cast(float, ((unsigned)u) << 16);
}

__device__ __forceinline__ void gload16(const u16* g, u16* l) {
    __builtin_amdgcn_global_load_lds(
        (const __attribute__((address_space(1))) unsigned int*)g,
        (__attribute__((address_space(3))) unsigned int*)l, 16, 0, 0);
}

// ---------------------------------------------------------------------------
// Weight cast: phi_w+theta_w -> Wcat bf16 [512][512]; W_w -> Wwb bf16 [512][256]
// ---------------------------------------------------------------------------
__global__ __launch_bounds__(256) void castw_kernel(
    const float* __restrict__ phi_w, const float* __restrict__ theta_w,
    const float* __restrict__ Ww,
    u16* __restrict__ Wcat, u16* __restrict__ Wwb)
{
    int i = blockIdx.x * 256 + threadIdx.x;
    if (i < 262144) {
        float v = (i < 131072) ? phi_w[i] : theta_w[i - 131072];
        Wcat[i] = (u16)bf16_1(v);
    } else {
        int j = i - 262144;
        Wwb[j] = (u16)bf16_1(Ww[j]);
    }
}

// ---------------------------------------------------------------------------
// castx: x fp32 [b][512 c][9216 hw] -> xT bf16 [b][9216 hw][512 c]
// ---------------------------------------------------------------------------
__global__ __launch_bounds__(256) void castx_kernel(
    const float* __restrict__ x, u16* __restrict__ xT)
{
    const int t = threadIdx.x;
    const int tx = t & 15, ty = t >> 4;
    const int b = blockIdx.z;
    const int c0 = blockIdx.y * 64;
    const int hw0 = blockIdx.x * 64;

    const float* xb = x + ((size_t)b * CIN + c0 + ty * 4) * HWN + hw0 + tx * 4;
    float4 v[4];
#pragma unroll
    for (int q = 0; q < 4; ++q)
        v[q] = *(const float4*)(xb + (size_t)q * HWN);

    u16* dst = xT + ((size_t)b * HWN + hw0 + tx * 4) * CIN + c0 + ty * 4;
    const float* f = (const float*)v;
#pragma unroll
    for (int p = 0; p < 4; ++p) {
        uint2 o = {bf16_pack(f[0 * 4 + p], f[1 * 4 + p]),
                   bf16_pack(f[2 * 4 + p], f[3 * 4 + p])};
        *(uint2*)(dst + (size_t)p * CIN) = o;
    }
}

// ---------------------------------------------------------------------------
// MFMA GEMM, 3-buffer counted-vmcnt pipeline (T4):
//   iter s: { stage(s+2) -> vmcnt(8): tile s landed (FIFO), queue never
//   drains mid-loop -> barrier -> compute(s) -> barrier (buffer-reuse guard) }
//   Loads get ~2 compute-tiles to land. BK=32, 48 KB LDS, 3 blocks/CU.
//   Buffer safety: stage(s+2) writes buf[(s+2)%3]; its last readers finished
//   at iter s-1's trailing barrier.
// ---------------------------------------------------------------------------
template<int KDIM, int MODE>
__global__ __launch_bounds__(256, 3) void gemm_kernel(
    const u16* __restrict__ A,
    const u16* __restrict__ Bw,
    const float* __restrict__ b0, const float* __restrict__ b1,
    const float* __restrict__ resid,
    void* __restrict__ out0_, void* __restrict__ out1_)
{
    __shared__ u16 As[3][128 * 32];
    __shared__ u16 Bs[3][128 * 32];

    constexpr int NSTEP = KDIM / 32;
    constexpr int NWG = 72 * 4 * NB;

    // bijective XCD swizzle, by-minor within each XCD chunk (A L2-resident)
    const int id = blockIdx.x;
    const int swz = (id & 7) * (NWG / 8) + (id >> 3);
    const int u = swz % 288;
    const int bz = swz / 288;
    const int by = u & 3;
    const int bx = u >> 2;

    const int t = threadIdx.x;
    const int m0 = bx * 128;
    const int n0 = by * 128;
    const int w = t >> 6, l = t & 63;
    const int wr = w >> 1, wc = w & 1;
    const int g = l >> 4, li = l & 15;

    const u16* Ab = A + (size_t)bz * HWN * KDIM + (size_t)m0 * KDIM;
    const u16* Bb = Bw + (size_t)n0 * KDIM;

    f32x4 zero = {0.f, 0.f, 0.f, 0.f};
    f32x4 acc[4][4];
#pragma unroll
    for (int i = 0; i < 4; ++i)
#pragma unroll
        for (int j = 0; j < 4; ++j) acc[i][j] = zero;

    // stage one K=32 tile into buffer step%3 (4 gload16/thread = 4 vmcnt
    // units/wave). LDS linear (lane-contiguous), swizzle folded into source.
    auto stage = [&](int step) {
        const int buf = step % 3;
#pragma unroll
        for (int j = 0; j < 2; ++j) {
            int c = j * 256 + t;
            int row = c >> 2, slot = c & 3;
            int ss = slot ^ ((row >> 1) & 3);
            gload16(Ab + (size_t)row * KDIM + step * 32 + ss * 8, &As[buf][c * 8]);
        }
#pragma unroll
        for (int j = 0; j < 2; ++j) {
            int c = j * 256 + t;
            int row = c >> 2, slot = c & 3;
            int ss = slot ^ ((row >> 1) & 3);
            gload16(Bb + (size_t)row * KDIM + step * 32 + ss * 8, &Bs[buf][c * 8]);
        }
    };

    // prologue: 2 tiles in flight
    stage(0);
    stage(1);

#pragma unroll 1
    for (int s = 0; s < NSTEP; ++s) {
        if (s + 2 < NSTEP) {
            stage(s + 2);
            // outstanding: [s:4][s+1:4][s+2:4] -> all but 8 = tile s landed
            asm volatile("s_waitcnt vmcnt(8)" ::: "memory");
        } else if (s + 1 < NSTEP) {
            asm volatile("s_waitcnt vmcnt(4)" ::: "memory");
        } else {
            asm volatile("s_waitcnt vmcnt(0)" ::: "memory");
        }
        __builtin_amdgcn_s_barrier();        // all waves' tile-s loads landed
        __builtin_amdgcn_sched_barrier(0);

        const int cb = s % 3;
        bf16x8 af[4], bv[4];
#pragma unroll
        for (int mi = 0; mi < 4; ++mi) {
            int r = wr * 64 + mi * 16 + li;
            int sl = g ^ ((r >> 1) & 3);
            af[mi] = *(const bf16x8*)&As[cb][r * 32 + sl * 8];
        }
#pragma unroll
        for (int ni = 0; ni < 4; ++ni) {
            int r = wc * 64 + ni * 16 + li;
            int sl = g ^ ((r >> 1) & 3);
            bv[ni] = *(const bf16x8*)&Bs[cb][r * 32 + sl * 8];
        }
#pragma unroll
        for (int mi = 0; mi < 4; ++mi)
#pragma unroll
            for (int ni = 0; ni < 4; ++ni)
                acc[mi][ni] = __builtin_amdgcn_mfma_f32_16x16x32_bf16(
                    af[mi], bv[ni], acc[mi][ni], 0, 0, 0);

        // trailing barrier: all waves done reading buf[s%3] before anyone
        // issues stage(s+3) (which reuses this buffer) next iteration.
        __builtin_amdgcn_s_barrier();
    }

    // ---- epilogue: transposed store D[m][n] -> dst[n][m] ----
#pragma unroll
    for (int ni = 0; ni < 4; ++ni) {
        int n = n0 + wc * 64 + ni * 16 + li;
        if constexpr (MODE == 0) {
            float bias = (n < 256) ? b0[n] : b1[n - 256];
            u16* dst = (u16*)((n < 256) ? out0_ : out1_) + ((size_t)bz * 256 + (n & 255)) * HWN;
#pragma unroll
            for (int mi = 0; mi < 4; ++mi) {
                int m = m0 + wr * 64 + mi * 16 + (g << 2);
                f32x4 v = acc[mi][ni];
                float e0 = fmaxf(v.x + bias, 0.f), e1 = fmaxf(v.y + bias, 0.f);
                float e2 = fmaxf(v.z + bias, 0.f), e3 = fmaxf(v.w + bias, 0.f);
                uint2 pk = {bf16_pack(e0, e1), bf16_pack(e2, e3)};
                *(uint2*)(dst + m) = pk;
            }
        } else {
            float bias = b0[n];
            float* dst = (float*)out0_ + ((size_t)bz * 512 + n) * HWN;
            const float* res = resid + ((size_t)bz * 512 + n) * HWN;
#pragma unroll
            for (int mi = 0; mi < 4; ++mi) {
                int m = m0 + wr * 64 + mi * 16 + (g << 2);
                f32x4 v = acc[mi][ni];
                float4 rx = *(const float4*)(res + m);
                float4 o = {v.x + bias + rx.x, v.y + bias + rx.y,
                            v.z + bias + rx.z, v.w + bias + rx.w};
                *(float4*)(dst + m) = o;
            }
        }
    }
}

// ---------------------------------------------------------------------------
// SPP pooling, fp32 input (x) -> xp [B][512][110] fp32
// ---------------------------------------------------------------------------
__global__ __launch_bounds__(256) void pool_x_kernel(
    const float* __restrict__ in, float* __restrict__ out)
{
    __shared__ float ps[576];
    const int plane = blockIdx.x;
    const float* p = in + (size_t)plane * HWN;
    const int t = threadIdx.x;

    for (int i = t; i < 576; i += 256) {
        int bh = i / 24, bw = i % 24;
        float s = 0.f;
#pragma unroll
        for (int r = 0; r < 4; ++r) {
            float4 v = *(const float4*)&p[(bh * 4 + r) * 96 + bw * 4];
            s += v.x + v.y + v.z + v.w;
        }
        ps[i] = s;
    }
    __syncthreads();

    if (t < KP) {
        float s = 0.f;
        if (t == 0) {
            for (int i = 0; i < 576; ++i) s += ps[i];
            s *= (1.0f / 9216.0f);
        } else if (t < 10) {
            int idx = t - 1, bi = idx / 3, bj = idx % 3;
            for (int r = 0; r < 8; ++r)
                for (int c = 0; c < 8; ++c)
                    s += ps[(bi * 8 + r) * 24 + bj * 8 + c];
            s *= (1.0f / 1024.0f);
        } else if (t < 46) {
            int idx = t - 10, bi = idx / 6, bj = idx % 6;
            for (int r = 0; r < 4; ++r)
                for (int c = 0; c < 4; ++c)
                    s += ps[(bi * 4 + r) * 24 + bj * 4 + c];
            s *= (1.0f / 256.0f);
        } else {
            int idx = t - 46, bi = idx / 8, bj = idx % 8;
            for (int r = 0; r < 3; ++r)
                for (int c = 0; c < 3; ++c)
                    s += ps[(bi * 3 + r) * 24 + bj * 3 + c];
            s *= (1.0f / 144.0f);
        }
        out[(size_t)plane * KP + t] = s;
    }
}

// ---------------------------------------------------------------------------
// SPP pooling, bf16 input (theta) -> tpT [B][128][256] bf16 transposed, padded
// ---------------------------------------------------------------------------
__global__ __launch_bounds__(256) void pool_t_kernel(
    const u16* __restrict__ in, u16* __restrict__ outT)
{
    __shared__ float ps[576];
    const int plane = blockIdx.x;
    const int b = plane >> 8, c = plane & 255;
    const u16* p = in + (size_t)plane * HWN;
    const int t = threadIdx.x;

    for (int i = t; i < 576; i += 256) {
        int bh = i / 24, bw = i % 24;
        float s = 0.f;
#pragma unroll
        for (int r = 0; r < 4; ++r) {
            ushort4 v = *(const ushort4*)&p[(bh * 4 + r) * 96 + bw * 4];
            s += b2f(v.x) + b2f(v.y) + b2f(v.z) + b2f(v.w);
        }
        ps[i] = s;
    }
    __syncthreads();

    if (t < 128) {
        float s = 0.f;
        if (t == 0) {
            for (int i = 0; i < 576; ++i) s += ps[i];
            s *= (1.0f / 9216.0f);
        } else if (t < 10) {
            int idx = t - 1, bi = idx / 3, bj = idx % 3;
            for (int r = 0; r < 8; ++r)
                for (int cc = 0; cc < 8; ++cc)
                    s += ps[(bi * 8 + r) * 24 + bj * 8 + cc];
            s *= (1.0f / 1024.0f);
        } else if (t < 46) {
            int idx = t - 10, bi = idx / 6, bj = idx % 6;
            for (int r = 0; r < 4; ++r)
                for (int cc = 0; cc < 4; ++cc)
                    s += ps[(bi * 4 + r) * 24 + bj * 4 + cc];
            s *= (1.0f / 256.0f);
        } else if (t < KP) {
            int idx = t - 46, bi = idx / 8, bj = idx % 8;
            for (int r = 0; r < 3; ++r)
                for (int cc = 0; cc < 3; ++cc)
                    s += ps[(bi * 3 + r) * 24 + bj * 3 + cc];
            s *= (1.0f / 144.0f);
        } else {
            s = 0.f;
        }
        outT[((size_t)b * 128 + t) * 256 + c] = (u16)bf16_1(s);
    }
}

// ---------------------------------------------------------------------------
// gamma_p k-minor, L2-efficient (R10 version): block = 8 k values x 256 o.
// ---------------------------------------------------------------------------
__global__ __launch_bounds__(256) void gammap_kernel(
    const float* __restrict__ xp,   // [B][512][110]
    const float* __restrict__ gw,   // [256][512]
    const float* __restrict__ gb,   // [256]
    u16* __restrict__ gp)           // [B][256][128]
{
    __shared__ float xc[8][512];
    const int kb = blockIdx.x * 8, b = blockIdx.y;
    const int t = threadIdx.x;

#pragma unroll
    for (int j = 0; j < 16; ++j) {
        int idx = j * 256 + t;
        int kk = idx >> 9, c = idx & 511;
        int k = kb + kk;
        xc[kk][c] = (k < KP) ? xp[((size_t)b * CIN + c) * KP + k] : 0.f;
    }
    __syncthreads();

    float bias = gb[t];
    float acc[8];
#pragma unroll
    for (int kk = 0; kk < 8; ++kk) acc[kk] = bias;

    const float* wrow = gw + (size_t)t * CIN;
#pragma unroll 2
    for (int c = 0; c < CIN; c += 4) {
        float4 wv = *(const float4*)&wrow[c];
#pragma unroll
        for (int kk = 0; kk < 8; ++kk) {
            acc[kk] = fmaf(wv.x, xc[kk][c], acc[kk]);
            acc[kk] = fmaf(wv.y, xc[kk][c + 1], acc[kk]);
            acc[kk] = fmaf(wv.z, xc[kk][c + 2], acc[kk]);
            acc[kk] = fmaf(wv.w, xc[kk][c + 3], acc[kk]);
        }
    }

    ushort4 o0, o1;
    o0.x = (u16)bf16_1(acc[0]); o0.y = (u16)bf16_1(acc[1]);
    o0.z = (u16)bf16_1(acc[2]); o0.w = (u16)bf16_1(acc[3]);
    o1.x = (u16)bf16_1(acc[4]); o1.y = (u16)bf16_1(acc[5]);
    o1.z = (u16)bf16_1(acc[6]); o1.w = (u16)bf16_1(acc[7]);
    u16* dst = gp + ((size_t)b * 256 + t) * 128 + kb;
    *(ushort4*)(dst) = o0;
    *(ushort4*)(dst + 4) = o1;
}

// ---------------------------------------------------------------------------
// MFMA attention, 64-ci blocks (R10 version, unchanged).
// ---------------------------------------------------------------------------
__global__ __launch_bounds__(256, 4) void attn_kernel(
    const u16* __restrict__ phi,   // [B][256][9216] bf16
    const u16* __restrict__ tpT,   // [B][128][256] bf16
    const u16* __restrict__ gp,    // [B][256][128] bf16
    u16* __restrict__ y2T)         // [B][9216 hw'][256 ci] bf16
{
    __shared__ __align__(16) char smem[40960];
    u16* As = (u16*)smem;
    u16* Bs = (u16*)(smem + 8192);
    char* Pb = smem + 24576;
    u16* Gs = (u16*)smem;

    const int t = threadIdx.x;
    const int w = t >> 6, l = t & 63;
    const int g = l >> 4, li = l & 15;
    const int b = blockIdx.y;
    const int rr = blockIdx.x >> 2;
    const int ci0 = (blockIdx.x & 3) << 6;

    const u16* phib = phi + (size_t)b * (OIN * HWN);
    const u16* tpb  = tpT + (size_t)b * (128 * 256);
    const u16* gpb  = gp  + (size_t)b * (256 * 128);

    const int srow = t >> 3;
    const int su = t & 7;

    f32x4 zero = {0.f, 0.f, 0.f, 0.f};
    f32x4 acc[8];
#pragma unroll
    for (int j = 0; j < 8; ++j) acc[j] = zero;

    for (int kt = 0; kt < 256; kt += 64) {
#pragma unroll
        for (int cc = 0; cc < 2; ++cc) {
            int row = cc * 32 + srow;
            int ss = su ^ (row & 7);
            gload16(phib + (size_t)(ci0 + row) * HWN + rr * 256 + kt + ss * 8,
                    &As[(row * 8 + su) * 8]);
        }
#pragma unroll
        for (int cc = 0; cc < 4; ++cc) {
            int row = cc * 32 + srow;
            int ss = su ^ (row & 7);
            gload16(tpb + (size_t)row * 256 + kt + ss * 8,
                    &Bs[(row * 8 + su) * 8]);
        }
        __syncthreads();

#pragma unroll
        for (int h = 0; h < 2; ++h) {
            int r = w * 16 + li;
            bf16x8 af = *(const bf16x8*)&As[r * 64 + (((h * 4 + g) ^ (r & 7)) << 3)];
            bf16x8 bfr[8];
#pragma unroll
            for (int ni = 0; ni < 8; ++ni) {
                int rb = ni * 16 + li;
                bfr[ni] = *(const bf16x8*)&Bs[rb * 64 + (((h * 4 + g) ^ (rb & 7)) << 3)];
            }
#pragma unroll
            for (int ni = 0; ni < 8; ++ni)
                acc[ni] = __builtin_amdgcn_mfma_f32_16x16x32_bf16(
                    af, bfr[ni], acc[ni], 0, 0, 0);
        }
        __syncthreads();
    }

    bool vm[8];
#pragma unroll
    for (int ni = 0; ni < 8; ++ni) vm[ni] = (ni * 16 + li) < KP;

#pragma unroll
    for (int r = 0; r < 4; ++r) {
        float mx = -1e30f;
#pragma unroll
        for (int ni = 0; ni < 8; ++ni)
            if (vm[ni]) mx = fmaxf(mx, acc[ni][r] * SCL);
        mx = fmaxf(mx, __shfl_xor(mx, 1));
        mx = fmaxf(mx, __shfl_xor(mx, 2));
        mx = fmaxf(mx, __shfl_xor(mx, 4));
        mx = fmaxf(mx, __shfl_xor(mx, 8));
        float s = 0.f;
#pragma unroll
        for (int ni = 0; ni < 8; ++ni) {
            float e = vm[ni] ? __expf(acc[ni][r] * SCL - mx) : 0.f;
            acc[ni][r] = e;
            s += e;
        }
        s += __shfl_xor(s, 1);
        s += __shfl_xor(s, 2);
        s += __shfl_xor(s, 4);
        s += __shfl_xor(s, 8);
        float inv = 1.0f / s;
#pragma unroll
        for (int ni = 0; ni < 8; ++ni) acc[ni][r] *= inv;
    }
#pragma unroll
    for (int ni = 0; ni < 8; ++ni)
#pragma unroll
        for (int r = 0; r < 4; ++r) {
            int row = w * 16 + g * 4 + r;
            int col = ni * 16 + li;
            *(short*)(Pb + row * 256 + (((col >> 3) ^ (row & 7)) << 4) + ((col & 7) << 1)) =
                (short)bf16_1(acc[ni][r]);
        }

    f32x4 acc2[16];
#pragma unroll
    for (int j = 0; j < 16; ++j) acc2[j] = zero;

#pragma unroll 1
    for (int ch = 0; ch < 4; ++ch) {
#pragma unroll
        for (int j = 0; j < 4; ++j) {
            int row = j * 64 + (t >> 2);
            int slot = t & 3;
            int ss = slot ^ (row & 3);
            gload16(gpb + (size_t)row * 128 + ch * 32 + ss * 8,
                    &Gs[(j * 256 + t) * 8]);
        }
        __syncthreads();

        int prow = w * 16 + li;
        bf16x8 a2 = *(const bf16x8*)(Pb + prow * 256 + (((ch * 4 + g) ^ (prow & 7)) << 4));
#pragma unroll
        for (int cf = 0; cf < 16; ++cf) {
            int crow = cf * 16 + li;
            bf16x8 bv = *(const bf16x8*)((const char*)Gs + crow * 64 + ((g ^ (crow & 3)) << 4));
            acc2[cf] = __builtin_amdgcn_mfma_f32_16x16x32_bf16(a2, bv, acc2[cf], 0, 0, 0);
        }
        __syncthreads();
    }

#pragma unroll
    for (int cf = 0; cf < 16; ++cf) {
        int c = cf * 16 + li;
        int cib = w * 16 + g * 4;
        int e0 = c * 64 + (cib ^ ((li & 7) << 3));
        unsigned d0 = bf16_pack(acc2[cf][0], acc2[cf][1]);
        unsigned d1 = bf16_pack(acc2[cf][2], acc2[cf][3]);
        *(unsigned*)(smem + (size_t)e0 * 2) = d0;
        *(unsigned*)(smem + (size_t)e0 * 2 + 4) = d1;
    }

    __syncthreads();

    {
        int c = t;
        u16* dst = y2T + ((size_t)b * HWN + rr * 256 + c) * 256 + ci0;
#pragma unroll
        for (int j = 0; j < 8; ++j) {
            uint4 v = *(const uint4*)(smem + c * 128 + ((j ^ (c & 7)) << 4));
            *(uint4*)(dst + j * 8) = v;
        }
    }
}

extern "C" void kernel_launch(void* const* d_in, const int* in_sizes, int n_in,
                              void* d_out, int out_size, void* d_ws, size_t ws_size,
                              hipStream_t stream)
{
    const float* x       = (const float*)d_in[0];
    const float* phi_w   = (const float*)d_in[1];
    const float* phi_b   = (const float*)d_in[2];
    const float* theta_w = (const float*)d_in[3];
    const float* theta_b = (const float*)d_in[4];
    const float* gamma_w = (const float*)d_in[5];
    const float* gamma_b = (const float*)d_in[6];
    const float* W_w     = (const float*)d_in[7];
    const float* W_b     = (const float*)d_in[8];
    float* out = (float*)d_out;

    char* p = (char*)d_ws;
    u16* xT     = (u16*)p;  p += (size_t)NB * HWN * CIN * 2;   // 75.5 MB
    u16* phi_bf = (u16*)p;  p += (size_t)NB * OIN * HWN * 2;   // 37.7 MB
    u16* th_y2  = (u16*)p;  p += (size_t)NB * OIN * HWN * 2;   // 37.7 MB (theta, then y2T)
    float* xp   = (float*)p; p += (size_t)NB * CIN * KP * 4;
    u16* tpT    = (u16*)p;  p += (size_t)NB * 128 * 256 * 2;
    u16* gp     = (u16*)p;  p += (size_t)NB * 256 * 128 * 2;
    u16* Wcat   = (u16*)p;  p += 512 * 512 * 2;
    u16* Wwb    = (u16*)p;  p += 512 * 256 * 2;

    castw_kernel<<<1536, 256, 0, stream>>>(phi_w, theta_w, W_w, Wcat, Wwb);
    castx_kernel<<<dim3(144, 8, NB), 256, 0, stream>>>(x, xT);
    // pool_x right after castx: x still L3-resident from castx's read
    pool_x_kernel<<<dim3(NB * CIN), 256, 0, stream>>>(x, xp);
    gemm_kernel<512, 0><<<dim3(72 * 4 * NB), 256, 0, stream>>>(
        xT, Wcat, phi_b, theta_b, nullptr, phi_bf, th_y2);
    pool_t_kernel<<<dim3(NB * OIN), 256, 0, stream>>>(th_y2, tpT);
    gammap_kernel<<<dim3(16, NB), 256, 0, stream>>>(xp, gamma_w, gamma_b, gp);
    attn_kernel<<<dim3(144, NB), 256, 0, stream>>>(phi_bf, tpT, gp, th_y2);
    gemm_kernel<256, 1><<<dim3(72 * 4 * NB), 256, 0, stream>>>(
        th_y2, Wwb, W_b, nullptr, x, out, nullptr);
}